// Round 3
// baseline (789.001 us; speedup 1.0000x reference)
//
#include <hip/hip_runtime.h>

typedef unsigned short u16;
typedef unsigned int u32;
typedef unsigned long long u64;

#define N_SITES 500000
#define CIN 32
#define COUT 32
#define DD 128
#define HHH 128
#define WWW 128
#define KVOL 125
#define EPSV 1e-4f
#define NVOX (4*DD*HHH*WWW)           // 8,388,608 = 8192 * 1024
#define RED_BLOCKS 504
#define CNT_BLOCKS 8192
#define NSLOT 500224                  // 1954 * 256 (padded site slots)
#define ZROW  N_SITES                 // zero feature row index in ybuf
#define SENTI (NVOX+4)                // sentinel window start (pad region, all -1)

typedef short v8s __attribute__((ext_vector_type(8)));
typedef float v16f __attribute__((ext_vector_type(16)));

// ---------- helpers ----------
__device__ __forceinline__ u16 f2bf(float f){
  union { float f; u32 i; } v; v.f = f;
  u32 r = v.i + 0x7fffu + ((v.i >> 16) & 1u);
  return (u16)(r >> 16);
}

__device__ __forceinline__ u32 rowsel(int nv){   // nv>=0 ? nv : ZROW  (one v_min_u32)
  u32 a = (u32)nv, b = (u32)ZROW;
  return a < b ? a : b;
}

__device__ __forceinline__ v8s lds_frag(const char* a){  // 16B fragment at 8B-aligned addr
  union { v8s v; u64 q[2]; } u;
  u.q[0] = *(const u64*)(a);
  u.q[1] = *(const u64*)(a + 8);
  return u.v;
}

// ---------- BN stage 1: per-block partial sums (f32 input) ----------
__launch_bounds__(256)
__global__ void bn_reduce(const float* __restrict__ x, float* __restrict__ partial){
  __shared__ float ssum[8][32], ssq[8][32];
  int tid = threadIdx.x;
  int c   = tid & 31;
  int row = tid >> 5;
  float s = 0.f, q = 0.f;
  for(int site = blockIdx.x*8 + row; site < N_SITES; site += gridDim.x*8){
    float f = x[(size_t)site*32 + c];
    s += f; q += f*f;
  }
  ssum[row][c] = s; ssq[row][c] = q;
  __syncthreads();
  if(tid < 32){
    float ts = 0.f, tq = 0.f;
    #pragma unroll
    for(int r = 0; r < 8; r++){ ts += ssum[r][tid]; tq += ssq[r][tid]; }
    partial[blockIdx.x*64 + tid]      = ts;
    partial[blockIdx.x*64 + 32 + tid] = tq;
  }
}

// ---------- BN stage 2: finalize scale/shift ----------
__global__ void bn_finalize(const float* __restrict__ partial, const float* __restrict__ gamma,
                            const float* __restrict__ beta, float* __restrict__ ss, int nblk){
  int tid = threadIdx.x;
  if(tid >= 32) return;
  float s = 0.f, q = 0.f;
  for(int b = 0; b < nblk; b++){
    s += partial[b*64 + tid];
    q += partial[b*64 + 32 + tid];
  }
  float mean = s / (float)N_SITES;
  float var  = q / (float)N_SITES - mean*mean;   // biased, matches reference
  float scale = gamma[tid] * rsqrtf(var + EPSV);
  ss[tid]      = scale;
  ss[32 + tid] = beta[tid] - mean*scale;
}

// ---------- y = bf16(relu(x*scale+shift)) into workspace ----------
__launch_bounds__(256)
__global__ void bn_apply_y(const float4* __restrict__ xv, const float* __restrict__ ss,
                           uint4* __restrict__ yv){
  __shared__ float sc[64];
  int tid = threadIdx.x;
  if(tid < 64) sc[tid] = ss[tid];
  __syncthreads();
  const int total = N_SITES*CIN/8;            // 2,000,000 chunks of 8
  int stride = gridDim.x*256;
  for(int i = blockIdx.x*256 + tid; i < total; i += stride){
    int c0 = (i & 3) * 8;
    float4 a = xv[2*i], b = xv[2*i+1];
    float f[8] = {a.x,a.y,a.z,a.w,b.x,b.y,b.z,b.w};
    #pragma unroll
    for(int j = 0; j < 8; j++) f[j] = fmaxf(f[j]*sc[c0+j] + sc[32+c0+j], 0.f);
    uint4 o;
    o.x = ((u32)f2bf(f[1])<<16) | f2bf(f[0]);
    o.y = ((u32)f2bf(f[3])<<16) | f2bf(f[2]);
    o.z = ((u32)f2bf(f[5])<<16) | f2bf(f[4]);
    o.w = ((u32)f2bf(f[7])<<16) | f2bf(f[6]);
    yv[i] = o;
  }
}

// ---------- scatter site indices into dense voxel grid ----------
__launch_bounds__(256)
__global__ void build_grid(const int4* __restrict__ coords, int* __restrict__ grid){
  int i = blockIdx.x*256 + threadIdx.x;
  if(i >= N_SITES) return;
  int4 c = coords[i];  // (b, z, y, x)
  grid[((c.x*DD + c.y)*HHH + c.z)*WWW + c.w] = i;
}

// ---------- per-1024-voxel-block active counts ----------
__launch_bounds__(256)
__global__ void count_blocks(const int* __restrict__ grid, int* __restrict__ blockcnt){
  int b = blockIdx.x, t = threadIdx.x;
  int cnt = 0;
  #pragma unroll
  for(int k = 0; k < 4; k++) cnt += (grid[b*1024 + k*256 + t] >= 0);
  #pragma unroll
  for(int o = 32; o > 0; o >>= 1) cnt += __shfl_down(cnt, o);
  __shared__ int wsum[4];
  if((t & 63) == 0) wsum[t >> 6] = cnt;
  __syncthreads();
  if(t == 0) blockcnt[b] = wsum[0] + wsum[1] + wsum[2] + wsum[3];
}

// ---------- exclusive prefix over 8192 block counts (one block) ----------
__launch_bounds__(1024)
__global__ void scan_blocks(const int* __restrict__ blockcnt, int* __restrict__ blockoff){
  __shared__ int s[1024];
  int t = threadIdx.x;
  int loc[8]; int v = 0;
  #pragma unroll
  for(int k = 0; k < 8; k++){ loc[k] = blockcnt[t*8 + k]; v += loc[k]; }
  s[t] = v; __syncthreads();
  for(int o = 1; o < 1024; o <<= 1){
    int add = (t >= o) ? s[t - o] : 0;
    __syncthreads();
    s[t] += add;
    __syncthreads();
  }
  int base = s[t] - v;
  #pragma unroll
  for(int k = 0; k < 8; k++){ blockoff[t*8 + k] = base; base += loc[k]; }
}

// ---------- ordered compaction: perm[j] = site ids in ascending voxel order ----------
__launch_bounds__(256)
__global__ void fill_perm(const int* __restrict__ grid, const int* __restrict__ blockoff,
                          int* __restrict__ perm){
  int b = blockIdx.x, t = threadIdx.x;
  int w = t >> 6, lane = t & 63;
  __shared__ int wcnt[4];
  __shared__ int carry;
  if(t == 0) carry = 0;
  __syncthreads();
  int base = blockoff[b];
  for(int p = 0; p < 4; p++){
    int v = b*1024 + p*256 + t;
    int s = grid[v];
    bool act = (s >= 0);
    u64 bal = __ballot(act);
    int pre = (int)__popcll(bal & ((1ull << lane) - 1ull));
    if(lane == 0) wcnt[w] = (int)__popcll(bal);
    __syncthreads();
    int woff = 0;
    for(int ww = 0; ww < w; ww++) woff += wcnt[ww];
    if(act) perm[base + carry + woff + pre] = s;
    int tot = wcnt[0] + wcnt[1] + wcnt[2] + wcnt[3];
    __syncthreads();
    if(t == 0) carry += tot;
    __syncthreads();
  }
}

// ---------- pad perm slots; zero the sentinel feature row ----------
__global__ void pad_perm(int* __restrict__ perm, u32* __restrict__ yzero){
  int t = threadIdx.x;
  if(t < NSLOT - N_SITES) perm[N_SITES + t] = perm[0];
  if(t < 16) yzero[t] = 0;                    // 64 B zero row at ZROW
}

// ---------- pack W f32 [125][cin][cout] into bf16 32x32x16 B-fragment order ----------
// wf element index i = ((off*2 + half)*64 + lane)*8 + j
// value = W[off][k][n], k = half*16 + (lane>>5)*8 + j, n = lane&31
__launch_bounds__(256)
__global__ void prep_wfrag(const float* __restrict__ w, u16* __restrict__ wf){
  int i = blockIdx.x*256 + threadIdx.x;
  if(i >= KVOL*2*64*8) return;
  int j    = i & 7;
  int lane = (i >> 3) & 63;
  int half = (i >> 9) & 1;
  int off  = i >> 10;
  int k = half*16 + ((lane >> 5) << 3) + j;
  int n = lane & 31;
  wf[i] = f2bf(w[off*1024 + k*32 + n]);
}

// ---------- submanifold sparse conv via MFMA gather-GEMM ----------
// v4: vectorized window probes (2x int4 per (group,row), extract 5 dx values
// via cndmask tree), pinned with a compiler memory fence against load-sinking
// (v3's VGPR=56 showed the scheduler defeated probe batching); per-plane
// weight staging in LDS (24B stride -> conflict-free, /4 L2 traffic);
// explicit gather pipeline with lead 2 + sched_group_barrier interleave.
__launch_bounds__(256, 2)
__global__ void conv_mfma(const u16* __restrict__ y, const int4* __restrict__ coords,
                          const u16* __restrict__ wf, const int* __restrict__ gridp,
                          const int* __restrict__ perm, float* __restrict__ out){
  const char* __restrict__ yc  = (const char*)y;
  const char* __restrict__ wfc = (const char*)wf;
  const char* __restrict__ gcp = (const char*)gridp;
  __shared__ u64 swf[9600];                 // 76,800 B: [25 off][2 half][64 lane] x 24B
  char* swfc = (char*)swf;

  int t = threadIdx.x;
  int l = t & 63;
  int r31 = l & 31;
  int h = l >> 5;
  u32 koff = (u32)h << 4;          // A k-half byte offset within a 64B row
  u32 lq24 = (u32)l * 24u;

  // bijective XCD swizzle
  int nwg = gridDim.x, bid = blockIdx.x;
  int xcd = bid & 7, rank = bid >> 3;
  int q8 = nwg >> 3, r8 = nwg & 7;
  int swz = (xcd < r8 ? xcd*(q8+1) : r8*(q8+1) + (xcd - r8)*q8) + rank;

  int slot = swz*256 + t;
  int p = perm[slot];
  int4 c = coords[p];                       // (b, z, y, x)
  int Z = c.y, Y = c.z, X = c.w;
  int base = ((c.x*DD + Z)*HHH + Y)*WWW + X;

  // per-group A-row site parameters (one-time redistribution)
  int b0 = __shfl(base, r31);
  int b1 = __shfl(base, 32 + r31);
  int x0 = __shfl(X, r31),  x1 = __shfl(X, 32 + r31);
  int y0 = __shfl(Y, r31),  y1 = __shfl(Y, 32 + r31);
  int z0 = __shfl(Z, r31),  z1 = __shfl(Z, 32 + r31);

  bool okx0[5], okx1[5], oky0[5], oky1[5];
  #pragma unroll
  for(int k = 0; k < 5; k++){
    okx0[k] = (u32)(x0 + k - 2) < WWW;
    okx1[k] = (u32)(x1 + k - 2) < WWW;
    oky0[k] = (u32)(y0 + k - 2) < HHH;
    oky1[k] = (u32)(y1 + k - 2) < HHH;
  }

  v16f acc0, acc1;
  #pragma unroll
  for(int i = 0; i < 16; i++){ acc0[i] = 0.f; acc1[i] = 0.f; }

  const int HW = HHH*WWW;

#define PROBE_ROW(r) { \
    bool v0 = okz0 && oky0[r]; \
    bool v1 = okz1 && oky1[r]; \
    int st0 = v0 ? (pb0 + ((r)-2)*WWW - 2) : SENTI; \
    int st1 = v1 ? (pb1 + ((r)-2)*WWW - 2) : SENTI; \
    int al0 = st0 & ~3, al1 = st1 & ~3; \
    sA[r] = st0 - al0; sB[r] = st1 - al1; \
    wA0[r] = *(const int4*)(gcp + (long)al0*4); \
    wA1[r] = *(const int4*)(gcp + (long)al0*4 + 16); \
    wB0[r] = *(const int4*)(gcp + (long)al1*4); \
    wB1[r] = *(const int4*)(gcp + (long)al1*4 + 16); \
  }

#define EXTRACT_ROW(r) { \
    int e0[8] = {wA0[r].x,wA0[r].y,wA0[r].z,wA0[r].w,wA1[r].x,wA1[r].y,wA1[r].z,wA1[r].w}; \
    int e1[8] = {wB0[r].x,wB0[r].y,wB0[r].z,wB0[r].w,wB1[r].x,wB1[r].y,wB1[r].z,wB1[r].w}; \
    bool sa2 = (sA[r] & 2) != 0, sa1 = (sA[r] & 1) != 0; \
    bool sb2 = (sB[r] & 2) != 0, sb1 = (sB[r] & 1) != 0; \
    _Pragma("unroll") \
    for(int k = 0; k < 5; k++){ \
      int t0 = sa2 ? e0[k+2] : e0[k]; \
      int t1 = sa2 ? e0[k+3] : e0[k+1]; \
      int va = sa1 ? t1 : t0; \
      nv0[(r)*5+k] = okx0[k] ? va : -1; \
      int u0 = sb2 ? e1[k+2] : e1[k]; \
      int u1 = sb2 ? e1[k+3] : e1[k+1]; \
      int vb = sb1 ? u1 : u0; \
      nv1[(r)*5+k] = okx1[k] ? vb : -1; \
    } \
  }

#define ISSUE(o) { \
    u32 lb = (u32)(o)*3072u + lq24; \
    wb0[o] = lds_frag(swfc + lb); \
    wb1[o] = lds_frag(swfc + lb + 1536u); \
    u32 ya0 = (rowsel(nv0[o]) << 6) + koff; \
    a00[o] = *(const v8s*)(yc + ya0); \
    a01[o] = *(const v8s*)(yc + ya0 + 32u); \
    u32 ya1 = (rowsel(nv1[o]) << 6) + koff; \
    a10[o] = *(const v8s*)(yc + ya1); \
    a11[o] = *(const v8s*)(yc + ya1 + 32u); \
  }

#define DOMFMA(o) { \
    acc0 = __builtin_amdgcn_mfma_f32_32x32x16_bf16(a00[o], wb0[o], acc0, 0, 0, 0); \
    acc0 = __builtin_amdgcn_mfma_f32_32x32x16_bf16(a01[o], wb1[o], acc0, 0, 0, 0); \
    acc1 = __builtin_amdgcn_mfma_f32_32x32x16_bf16(a10[o], wb0[o], acc1, 0, 0, 0); \
    acc1 = __builtin_amdgcn_mfma_f32_32x32x16_bf16(a11[o], wb1[o], acc1, 0, 0, 0); \
  }

  #pragma unroll 1
  for(int dz = -2; dz <= 2; dz++){
    bool okz0 = (u32)(z0 + dz) < DD;
    bool okz1 = (u32)(z1 + dz) < DD;
    int pb0 = b0 + dz*HW, pb1 = b1 + dz*HW;

    __syncthreads();                        // prior plane's LDS reads done
    // ---- stage this plane's weight fragments into LDS (16B -> 24B stride) ----
    {
      u32 pbase = (u32)((dz + 2) * 51200);  // 25 offsets x 2KB
      #pragma unroll
      for(int it = 0; it < 13; it++){
        int ch = it*256 + t;
        if(ch < 3200){
          uint4 v = *(const uint4*)(wfc + pbase + (u32)ch*16u);
          char* d = swfc + ch*24;
          *(u64*)(d)     = ((u64)v.y << 32) | v.x;
          *(u64*)(d + 8) = ((u64)v.w << 32) | v.z;
        }
      }
    }

    // ---- window probes, rows 0-2 (pinned against sinking) ----
    int4 wA0[5], wA1[5], wB0[5], wB1[5];
    int sA[5], sB[5];
    int nv0[25], nv1[25];
    PROBE_ROW(0) PROBE_ROW(1) PROBE_ROW(2)
    asm volatile("" ::: "memory");
    __syncthreads();                        // weights staged

    v8s wb0[25], wb1[25], a00[25], a01[25], a10[25], a11[25];
    EXTRACT_ROW(0)
    ISSUE(0) ISSUE(1)
    #pragma unroll
    for(int o = 0; o < 25; o++){
      if(o + 2 < 25){
        if((o + 2) % 5 == 0) EXTRACT_ROW((o + 2) / 5)
        ISSUE(o + 2)
      }
      if(o == 5){
        PROBE_ROW(3) PROBE_ROW(4)
        asm volatile("" ::: "memory");
      }
      DOMFMA(o)
      __builtin_amdgcn_sched_group_barrier(0x020, 4, 0);  // 4 VMEM read
      __builtin_amdgcn_sched_group_barrier(0x100, 4, 0);  // 4 DS read
      __builtin_amdgcn_sched_group_barrier(0x008, 4, 0);  // 4 MFMA
    }
  }

#undef PROBE_ROW
#undef EXTRACT_ROW
#undef ISSUE
#undef DOMFMA

  // epilogue: C/D layout col=lane&31, row=(reg&3)+8*(reg>>2)+4*(lane>>5)  [m74/m101]
  #pragma unroll
  for(int rg = 0; rg < 16; rg++){
    int row = (rg & 3) + ((rg >> 2) << 3) + (h << 2);
    int s0 = __shfl(p, row);
    int s1 = __shfl(p, 32 + row);
    out[(size_t)s0*32 + r31] = acc0[rg];
    out[(size_t)s1*32 + r31] = acc1[rg];
  }
}

extern "C" void kernel_launch(void* const* d_in, const int* in_sizes, int n_in,
                              void* d_out, int out_size, void* d_ws, size_t ws_size,
                              hipStream_t stream) {
  const float* feats  = (const float*)d_in[0];   // [N,32] f32
  const int4*  coords = (const int4*) d_in[1];   // [N,4] int32
  const float* gamma  = (const float*)d_in[2];   // [32] f32
  const float* beta   = (const float*)d_in[3];   // [32] f32
  const float* wght   = (const float*)d_in[4];   // [125,32,32] f32
  float* out = (float*)d_out;

  char* ws = (char*)d_ws;
  int*   grid_raw = (int*)  ws;                   // 33,554,560 B = (NVOX+32)*4 (8 pre + 24 post pad)
  int*   gridp    = grid_raw + 8;                 // usable grid [0, NVOX)
  u16*   ybuf     = (u16*)  (ws + 33554560);      // 32,000,064 B (500001 rows)
  u16*   wf       = (u16*)  (ws + 65554624);      //    256,000 B
  int*   perm     = (int*)  (ws + 65810624);      //  2,000,896 B
  int*   blockcnt = (int*)  (ws + 67811520);      //     32,768 B
  int*   blockoff = (int*)  (ws + 67844288);      //     32,768 B
  float* partial  = (float*)(ws + 67877056);      //    129,024 B
  float* ss       = (float*)(ws + 68006080);      //        256 B
  // total: 68,006,336 B

  hipMemsetAsync(grid_raw, 0xFF, (size_t)(NVOX+32)*4, stream);   // grid + pads = -1

  bn_reduce  <<<RED_BLOCKS, 256, 0, stream>>>(feats, partial);
  bn_finalize<<<1, 32, 0, stream>>>(partial, gamma, beta, ss, RED_BLOCKS);
  bn_apply_y <<<2048, 256, 0, stream>>>((const float4*)feats, ss, (uint4*)ybuf);

  build_grid  <<<(N_SITES+255)/256, 256, 0, stream>>>(coords, gridp);
  count_blocks<<<CNT_BLOCKS, 256, 0, stream>>>(gridp, blockcnt);
  scan_blocks <<<1, 1024, 0, stream>>>(blockcnt, blockoff);
  fill_perm   <<<CNT_BLOCKS, 256, 0, stream>>>(gridp, blockoff, perm);
  pad_perm    <<<1, 256, 0, stream>>>(perm, (u32*)(ybuf + (size_t)ZROW*32));

  prep_wfrag<<<(KVOL*2*64*8 + 255)/256, 256, 0, stream>>>(wght, wf);

  conv_mfma<<<NSLOT/256, 256, 0, stream>>>(ybuf, coords, wf, gridp, perm, out);
}

// Round 4
// 660.865 us; speedup vs baseline: 1.1939x; 1.1939x over previous
//
#include <hip/hip_runtime.h>

typedef unsigned short u16;
typedef unsigned int u32;
typedef unsigned long long u64;

#define N_SITES 500000
#define CIN 32
#define COUT 32
#define DD 128
#define HHH 128
#define WWW 128
#define KVOL 125
#define EPSV 1e-4f
#define NVOX (4*DD*HHH*WWW)           // 8,388,608 = 8192 * 1024
#define RED_BLOCKS 504
#define CNT_BLOCKS 8192
#define NSLOT 500224                  // 1954 * 256 (padded site slots)
#define ZROW  N_SITES                 // zero feature row index in ybuf

typedef short v8s __attribute__((ext_vector_type(8)));
typedef float v16f __attribute__((ext_vector_type(16)));

// ---------- helpers ----------
__device__ __forceinline__ u16 f2bf(float f){
  union { float f; u32 i; } v; v.f = f;
  u32 r = v.i + 0x7fffu + ((v.i >> 16) & 1u);
  return (u16)(r >> 16);
}

// ---------- BN stage 1: per-block partial sums (f32 input) ----------
__launch_bounds__(256)
__global__ void bn_reduce(const float* __restrict__ x, float* __restrict__ partial){
  __shared__ float ssum[8][32], ssq[8][32];
  int tid = threadIdx.x;
  int c   = tid & 31;
  int row = tid >> 5;
  float s = 0.f, q = 0.f;
  for(int site = blockIdx.x*8 + row; site < N_SITES; site += gridDim.x*8){
    float f = x[(size_t)site*32 + c];
    s += f; q += f*f;
  }
  ssum[row][c] = s; ssq[row][c] = q;
  __syncthreads();
  if(tid < 32){
    float ts = 0.f, tq = 0.f;
    #pragma unroll
    for(int r = 0; r < 8; r++){ ts += ssum[r][tid]; tq += ssq[r][tid]; }
    partial[blockIdx.x*64 + tid]      = ts;
    partial[blockIdx.x*64 + 32 + tid] = tq;
  }
}

// ---------- BN stage 2: finalize scale/shift ----------
__global__ void bn_finalize(const float* __restrict__ partial, const float* __restrict__ gamma,
                            const float* __restrict__ beta, float* __restrict__ ss, int nblk){
  int tid = threadIdx.x;
  if(tid >= 32) return;
  float s = 0.f, q = 0.f;
  for(int b = 0; b < nblk; b++){
    s += partial[b*64 + tid];
    q += partial[b*64 + 32 + tid];
  }
  float mean = s / (float)N_SITES;
  float var  = q / (float)N_SITES - mean*mean;   // biased, matches reference
  float scale = gamma[tid] * rsqrtf(var + EPSV);
  ss[tid]      = scale;
  ss[32 + tid] = beta[tid] - mean*scale;
}

// ---------- y = bf16(relu(x*scale+shift)) into workspace ----------
__launch_bounds__(256)
__global__ void bn_apply_y(const float4* __restrict__ xv, const float* __restrict__ ss,
                           uint4* __restrict__ yv){
  __shared__ float sc[64];
  int tid = threadIdx.x;
  if(tid < 64) sc[tid] = ss[tid];
  __syncthreads();
  const int total = N_SITES*CIN/8;            // 2,000,000 chunks of 8
  int stride = gridDim.x*256;
  for(int i = blockIdx.x*256 + tid; i < total; i += stride){
    int c0 = (i & 3) * 8;
    float4 a = xv[2*i], b = xv[2*i+1];
    float f[8] = {a.x,a.y,a.z,a.w,b.x,b.y,b.z,b.w};
    #pragma unroll
    for(int j = 0; j < 8; j++) f[j] = fmaxf(f[j]*sc[c0+j] + sc[32+c0+j], 0.f);
    uint4 o;
    o.x = ((u32)f2bf(f[1])<<16) | f2bf(f[0]);
    o.y = ((u32)f2bf(f[3])<<16) | f2bf(f[2]);
    o.z = ((u32)f2bf(f[5])<<16) | f2bf(f[4]);
    o.w = ((u32)f2bf(f[7])<<16) | f2bf(f[6]);
    yv[i] = o;
  }
}

// ---------- scatter site indices into dense voxel grid ----------
__launch_bounds__(256)
__global__ void build_grid(const int4* __restrict__ coords, int* __restrict__ grid){
  int i = blockIdx.x*256 + threadIdx.x;
  if(i >= N_SITES) return;
  int4 c = coords[i];  // (b, z, y, x)
  grid[((c.x*DD + c.y)*HHH + c.z)*WWW + c.w] = i;
}

// ---------- per-1024-voxel-block active counts ----------
__launch_bounds__(256)
__global__ void count_blocks(const int* __restrict__ grid, int* __restrict__ blockcnt){
  int b = blockIdx.x, t = threadIdx.x;
  int cnt = 0;
  #pragma unroll
  for(int k = 0; k < 4; k++) cnt += (grid[b*1024 + k*256 + t] >= 0);
  #pragma unroll
  for(int o = 32; o > 0; o >>= 1) cnt += __shfl_down(cnt, o);
  __shared__ int wsum[4];
  if((t & 63) == 0) wsum[t >> 6] = cnt;
  __syncthreads();
  if(t == 0) blockcnt[b] = wsum[0] + wsum[1] + wsum[2] + wsum[3];
}

// ---------- exclusive prefix over 8192 block counts (one block) ----------
__launch_bounds__(1024)
__global__ void scan_blocks(const int* __restrict__ blockcnt, int* __restrict__ blockoff){
  __shared__ int s[1024];
  int t = threadIdx.x;
  int loc[8]; int v = 0;
  #pragma unroll
  for(int k = 0; k < 8; k++){ loc[k] = blockcnt[t*8 + k]; v += loc[k]; }
  s[t] = v; __syncthreads();
  for(int o = 1; o < 1024; o <<= 1){
    int add = (t >= o) ? s[t - o] : 0;
    __syncthreads();
    s[t] += add;
    __syncthreads();
  }
  int base = s[t] - v;
  #pragma unroll
  for(int k = 0; k < 8; k++){ blockoff[t*8 + k] = base; base += loc[k]; }
}

// ---------- ordered compaction: perm[j] = site ids in ascending voxel order ----------
__launch_bounds__(256)
__global__ void fill_perm(const int* __restrict__ grid, const int* __restrict__ blockoff,
                          int* __restrict__ perm){
  int b = blockIdx.x, t = threadIdx.x;
  int w = t >> 6, lane = t & 63;
  __shared__ int wcnt[4];
  __shared__ int carry;
  if(t == 0) carry = 0;
  __syncthreads();
  int base = blockoff[b];
  for(int p = 0; p < 4; p++){
    int v = b*1024 + p*256 + t;
    int s = grid[v];
    bool act = (s >= 0);
    u64 bal = __ballot(act);
    int pre = (int)__popcll(bal & ((1ull << lane) - 1ull));
    if(lane == 0) wcnt[w] = (int)__popcll(bal);
    __syncthreads();
    int woff = 0;
    for(int ww = 0; ww < w; ww++) woff += wcnt[ww];
    if(act) perm[base + carry + woff + pre] = s;
    int tot = wcnt[0] + wcnt[1] + wcnt[2] + wcnt[3];
    __syncthreads();
    if(t == 0) carry += tot;
    __syncthreads();
  }
}

// ---------- pad perm slots; zero the sentinel feature row ----------
__global__ void pad_perm(int* __restrict__ perm, u32* __restrict__ yzero){
  int t = threadIdx.x;
  if(t < NSLOT - N_SITES) perm[N_SITES + t] = perm[0];
  if(t < 16) yzero[t] = 0;                    // 64 B zero row at ZROW
}

// ---------- pack W f32 [125][cin][cout] into bf16 32x32x16 B-fragment order ----------
// wf element index i = ((off*2 + half)*64 + lane)*8 + j
// value = W[off][k][n], k = half*16 + (lane>>5)*8 + j, n = lane&31
__launch_bounds__(256)
__global__ void prep_wfrag(const float* __restrict__ w, u16* __restrict__ wf){
  int i = blockIdx.x*256 + threadIdx.x;
  if(i >= KVOL*2*64*8) return;
  int j    = i & 7;
  int lane = (i >> 3) & 63;
  int half = (i >> 9) & 1;
  int off  = i >> 10;
  int k = half*16 + ((lane >> 5) << 3) + j;
  int n = lane & 31;
  wf[i] = f2bf(w[off*1024 + k*32 + n]);
}

// ---------- submanifold sparse conv via MFMA gather-GEMM ----------
// v5 = v3 (330us, VGPR=56) + two isolated changes:
//   (a) per-plane weight fragments staged in LDS (51.2KB, 16B stride ->
//       2-way aliasing within quarter-wave = free); removes 250 scattered
//       global wf reads/wave from the vector-memory path (moves to DS pipe).
//   (b) probe loads pinned with a compiler memory fence so all 50 stay in
//       flight (v3's VGPR=56 showed they were being sunk to point-of-use).
// NO gather pipeline arrays, NO launch_bounds VGPR cap (v4's 190MB of
// scratch spills came from exactly that combination).
__launch_bounds__(256)
__global__ void conv_mfma(const u16* __restrict__ y, const int4* __restrict__ coords,
                          const u16* __restrict__ wf, const int* __restrict__ grid,
                          const int* __restrict__ perm, float* __restrict__ out){
  const char* __restrict__ yc  = (const char*)y;
  const char* __restrict__ gc  = (const char*)grid;
  __shared__ v8s swf[3200];                 // 51,200 B: [25 off][2 half][64 lane] x 16B

  int t = threadIdx.x;
  int l = t & 63;
  int r31 = l & 31;
  int h = l >> 5;
  u32 koff = (u32)h << 4;          // A k-half byte offset within a 64B row

  // bijective XCD swizzle
  int nwg = gridDim.x, bid = blockIdx.x;
  int xcd = bid & 7, rank = bid >> 3;
  int q8 = nwg >> 3, r8 = nwg & 7;
  int swz = (xcd < r8 ? xcd*(q8+1) : r8*(q8+1) + (xcd - r8)*q8) + rank;

  int slot = swz*256 + t;
  int p = perm[slot];
  int4 c = coords[p];                       // (b, z, y, x)
  int Z = c.y, Y = c.z, X = c.w;
  int base = ((c.x*DD + Z)*HHH + Y)*WWW + X;

  // per-group A-row site parameters (one-time redistribution)
  int b0 = __shfl(base, r31);
  int b1 = __shfl(base, 32 + r31);
  int x0 = __shfl(X, r31),  x1 = __shfl(X, 32 + r31);
  int y0 = __shfl(Y, r31),  y1 = __shfl(Y, 32 + r31);
  int z0 = __shfl(Z, r31),  z1 = __shfl(Z, 32 + r31);

  bool okx0[5], okx1[5], oky0[5], oky1[5];
  #pragma unroll
  for(int k = 0; k < 5; k++){
    okx0[k] = (u32)(x0 + k - 2) < WWW;
    okx1[k] = (u32)(x1 + k - 2) < WWW;
    oky0[k] = (u32)(y0 + k - 2) < HHH;
    oky1[k] = (u32)(y1 + k - 2) < HHH;
  }

  v16f acc0, acc1;
  #pragma unroll
  for(int i = 0; i < 16; i++){ acc0[i] = 0.f; acc1[i] = 0.f; }

  const int HW = HHH*WWW;
  const uint4* __restrict__ wfv = (const uint4*)wf;

  #pragma unroll 1
  for(int dz = -2; dz <= 2; dz++){
    bool okz0 = (u32)(z0 + dz) < DD;
    bool okz1 = (u32)(z1 + dz) < DD;
    int pb0 = b0 + dz*HW, pb1 = b1 + dz*HW;

    __syncthreads();                        // prior plane's LDS reads complete
    // ---- stage this plane's 25 weight-fragment pairs into LDS ----
    {
      u32 pbase = (u32)((dz + 2) * 3200);   // in 16B chunks
      #pragma unroll
      for(int it = 0; it < 13; it++){
        int ch = it*256 + t;
        if(ch < 3200){
          uint4 v = wfv[pbase + ch];
          *(uint4*)&swf[ch] = v;
        }
      }
    }

    // ---- probe phase: 50 independent sentinel-masked loads in flight ----
    int nv0[25], nv1[25];
    #pragma unroll
    for(int r = 0; r < 5; r++){
      bool zy0 = okz0 && oky0[r];
      bool zy1 = okz1 && oky1[r];
      #pragma unroll
      for(int k = 0; k < 5; k++){
        int d = (r-2)*WWW + (k-2);
        u32 a0 = (zy0 && okx0[k]) ? (u32)(pb0 + d) : (u32)NVOX;
        u32 a1 = (zy1 && okx1[k]) ? (u32)(pb1 + d) : (u32)NVOX;
        nv0[r*5+k] = *(const int*)(gc + a0*4u);   // grid[NVOX] = -1 sentinel
        nv1[r*5+k] = *(const int*)(gc + a1*4u);
      }
    }
    asm volatile("" ::: "memory");          // pin probes (defeat load-sinking)
    __syncthreads();                        // weights staged

    // ---- process phase: branch-free straight line ----
    #pragma unroll
    for(int o = 0; o < 25; o++){
      v8s wb0 = swf[o*128 + l];             // ds_read_b128
      v8s wb1 = swf[o*128 + 64 + l];

      int n0 = nv0[o];
      u32 rw0 = (u32)n0 < (u32)ZROW ? (u32)n0 : (u32)ZROW;   // invalid -> zero row
      u32 ya0 = (rw0 << 6) + koff;
      v8s a00 = *(const v8s*)(yc + ya0);
      v8s a01 = *(const v8s*)(yc + ya0 + 32u);
      acc0 = __builtin_amdgcn_mfma_f32_32x32x16_bf16(a00, wb0, acc0, 0, 0, 0);
      acc0 = __builtin_amdgcn_mfma_f32_32x32x16_bf16(a01, wb1, acc0, 0, 0, 0);

      int n1 = nv1[o];
      u32 rw1 = (u32)n1 < (u32)ZROW ? (u32)n1 : (u32)ZROW;
      u32 ya1 = (rw1 << 6) + koff;
      v8s a10 = *(const v8s*)(yc + ya1);
      v8s a11 = *(const v8s*)(yc + ya1 + 32u);
      acc1 = __builtin_amdgcn_mfma_f32_32x32x16_bf16(a10, wb0, acc1, 0, 0, 0);
      acc1 = __builtin_amdgcn_mfma_f32_32x32x16_bf16(a11, wb1, acc1, 0, 0, 0);
    }
  }

  // epilogue: C/D layout col=lane&31, row=(reg&3)+8*(reg>>2)+4*(lane>>5)  [m74/m101]
  #pragma unroll
  for(int rg = 0; rg < 16; rg++){
    int row = (rg & 3) + ((rg >> 2) << 3) + (h << 2);
    int s0 = __shfl(p, row);
    int s1 = __shfl(p, 32 + row);
    out[(size_t)s0*32 + r31] = acc0[rg];
    out[(size_t)s1*32 + r31] = acc1[rg];
  }
}

extern "C" void kernel_launch(void* const* d_in, const int* in_sizes, int n_in,
                              void* d_out, int out_size, void* d_ws, size_t ws_size,
                              hipStream_t stream) {
  const float* feats  = (const float*)d_in[0];   // [N,32] f32
  const int4*  coords = (const int4*) d_in[1];   // [N,4] int32
  const float* gamma  = (const float*)d_in[2];   // [32] f32
  const float* beta   = (const float*)d_in[3];   // [32] f32
  const float* wght   = (const float*)d_in[4];   // [125,32,32] f32
  float* out = (float*)d_out;

  char* ws = (char*)d_ws;
  int*   grid     = (int*)  ws;                   // 33,554,496 B (NVOX+1 ints, padded)
  u16*   ybuf     = (u16*)  (ws + 33554496);      // 32,000,064 B (500001 rows)
  u16*   wf       = (u16*)  (ws + 65554560);      //    256,000 B
  int*   perm     = (int*)  (ws + 65810560);      //  2,000,896 B
  int*   blockcnt = (int*)  (ws + 67811456);      //     32,768 B
  int*   blockoff = (int*)  (ws + 67844224);      //     32,768 B
  float* partial  = (float*)(ws + 67876992);      //    129,024 B
  float* ss       = (float*)(ws + 68006016);      //        256 B
  // total: 68,006,272 B

  hipMemsetAsync(grid, 0xFF, (size_t)NVOX*4 + 4, stream);   // grid = -1, incl. sentinel

  bn_reduce  <<<RED_BLOCKS, 256, 0, stream>>>(feats, partial);
  bn_finalize<<<1, 32, 0, stream>>>(partial, gamma, beta, ss, RED_BLOCKS);
  bn_apply_y <<<2048, 256, 0, stream>>>((const float4*)feats, ss, (uint4*)ybuf);

  build_grid  <<<(N_SITES+255)/256, 256, 0, stream>>>(coords, grid);
  count_blocks<<<CNT_BLOCKS, 256, 0, stream>>>(grid, blockcnt);
  scan_blocks <<<1, 1024, 0, stream>>>(blockcnt, blockoff);
  fill_perm   <<<CNT_BLOCKS, 256, 0, stream>>>(grid, blockoff, perm);
  pad_perm    <<<1, 256, 0, stream>>>(perm, (u32*)(ybuf + (size_t)ZROW*32));

  prep_wfrag<<<(KVOL*2*64*8 + 255)/256, 256, 0, stream>>>(wght, wf);

  conv_mfma<<<NSLOT/256, 256, 0, stream>>>(ybuf, coords, wf, grid, perm, out);
}

// Round 5
// 646.294 us; speedup vs baseline: 1.2208x; 1.0225x over previous
//
#include <hip/hip_runtime.h>

typedef unsigned short u16;
typedef unsigned int u32;
typedef unsigned long long u64;

#define N_SITES 500000
#define CIN 32
#define COUT 32
#define DD 128
#define HHH 128
#define WWW 128
#define KVOL 125
#define EPSV 1e-4f
#define NVOX (4*DD*HHH*WWW)           // 8,388,608 = 8192 * 1024
#define RED_BLOCKS 504
#define CNT_BLOCKS 8192
#define NSLOT 500224                  // 1954 * 256 (padded site slots)
#define ZROW  N_SITES                 // zero feature row index in yperm

typedef short v8s __attribute__((ext_vector_type(8)));
typedef float v16f __attribute__((ext_vector_type(16)));

// ---------- helpers ----------
__device__ __forceinline__ u16 f2bf(float f){
  union { float f; u32 i; } v; v.f = f;
  u32 r = v.i + 0x7fffu + ((v.i >> 16) & 1u);
  return (u16)(r >> 16);
}

// ---------- BN stage 1: per-block partial sums (f32 input) ----------
__launch_bounds__(256)
__global__ void bn_reduce(const float* __restrict__ x, float* __restrict__ partial){
  __shared__ float ssum[8][32], ssq[8][32];
  int tid = threadIdx.x;
  int c   = tid & 31;
  int row = tid >> 5;
  float s = 0.f, q = 0.f;
  for(int site = blockIdx.x*8 + row; site < N_SITES; site += gridDim.x*8){
    float f = x[(size_t)site*32 + c];
    s += f; q += f*f;
  }
  ssum[row][c] = s; ssq[row][c] = q;
  __syncthreads();
  if(tid < 32){
    float ts = 0.f, tq = 0.f;
    #pragma unroll
    for(int r = 0; r < 8; r++){ ts += ssum[r][tid]; tq += ssq[r][tid]; }
    partial[blockIdx.x*64 + tid]      = ts;
    partial[blockIdx.x*64 + 32 + tid] = tq;
  }
}

// ---------- BN stage 2: finalize scale/shift ----------
__global__ void bn_finalize(const float* __restrict__ partial, const float* __restrict__ gamma,
                            const float* __restrict__ beta, float* __restrict__ ss, int nblk){
  int tid = threadIdx.x;
  if(tid >= 32) return;
  float s = 0.f, q = 0.f;
  for(int b = 0; b < nblk; b++){
    s += partial[b*64 + tid];
    q += partial[b*64 + 32 + tid];
  }
  float mean = s / (float)N_SITES;
  float var  = q / (float)N_SITES - mean*mean;   // biased, matches reference
  float scale = gamma[tid] * rsqrtf(var + EPSV);
  ss[tid]      = scale;
  ss[32 + tid] = beta[tid] - mean*scale;
}

// ---------- y = bf16(relu(x*scale+shift)) scattered into SLOT order ----------
// chunk i covers channels (i&3)*8.. of site i>>2; output row = rank[site]
// (voxel-order slot). 4 consecutive lanes write one 64B row -> single line.
__launch_bounds__(256)
__global__ void bn_apply_y(const float4* __restrict__ xv, const float* __restrict__ ss,
                           const int* __restrict__ rank, uint4* __restrict__ yv){
  __shared__ float sc[64];
  int tid = threadIdx.x;
  if(tid < 64) sc[tid] = ss[tid];
  __syncthreads();
  const int total = N_SITES*CIN/8;            // 2,000,000 chunks of 8
  int stride = gridDim.x*256;
  for(int i = blockIdx.x*256 + tid; i < total; i += stride){
    int c0 = (i & 3) * 8;
    int slot = rank[i >> 2];
    float4 a = xv[2*i], b = xv[2*i+1];
    float f[8] = {a.x,a.y,a.z,a.w,b.x,b.y,b.z,b.w};
    #pragma unroll
    for(int j = 0; j < 8; j++) f[j] = fmaxf(f[j]*sc[c0+j] + sc[32+c0+j], 0.f);
    uint4 o;
    o.x = ((u32)f2bf(f[1])<<16) | f2bf(f[0]);
    o.y = ((u32)f2bf(f[3])<<16) | f2bf(f[2]);
    o.z = ((u32)f2bf(f[5])<<16) | f2bf(f[4]);
    o.w = ((u32)f2bf(f[7])<<16) | f2bf(f[6]);
    yv[slot*4 + (i & 3)] = o;
  }
}

// ---------- scatter site indices into dense voxel grid ----------
__launch_bounds__(256)
__global__ void build_grid(const int4* __restrict__ coords, int* __restrict__ grid){
  int i = blockIdx.x*256 + threadIdx.x;
  if(i >= N_SITES) return;
  int4 c = coords[i];  // (b, z, y, x)
  grid[((c.x*DD + c.y)*HHH + c.z)*WWW + c.w] = i;
}

// ---------- per-1024-voxel-block active counts ----------
__launch_bounds__(256)
__global__ void count_blocks(const int* __restrict__ grid, int* __restrict__ blockcnt){
  int b = blockIdx.x, t = threadIdx.x;
  int cnt = 0;
  #pragma unroll
  for(int k = 0; k < 4; k++) cnt += (grid[b*1024 + k*256 + t] >= 0);
  #pragma unroll
  for(int o = 32; o > 0; o >>= 1) cnt += __shfl_down(cnt, o);
  __shared__ int wsum[4];
  if((t & 63) == 0) wsum[t >> 6] = cnt;
  __syncthreads();
  if(t == 0) blockcnt[b] = wsum[0] + wsum[1] + wsum[2] + wsum[3];
}

// ---------- exclusive prefix over 8192 block counts (one block) ----------
__launch_bounds__(1024)
__global__ void scan_blocks(const int* __restrict__ blockcnt, int* __restrict__ blockoff){
  __shared__ int s[1024];
  int t = threadIdx.x;
  int loc[8]; int v = 0;
  #pragma unroll
  for(int k = 0; k < 8; k++){ loc[k] = blockcnt[t*8 + k]; v += loc[k]; }
  s[t] = v; __syncthreads();
  for(int o = 1; o < 1024; o <<= 1){
    int add = (t >= o) ? s[t - o] : 0;
    __syncthreads();
    s[t] += add;
    __syncthreads();
  }
  int base = s[t] - v;
  #pragma unroll
  for(int k = 0; k < 8; k++){ blockoff[t*8 + k] = base; base += loc[k]; }
}

// ---------- ordered compaction: perm[slot] = site id; grid[v] := slot ----------
// After this kernel the dense grid maps voxel -> SLOT (voxel-order rank),
// which is the row index into the slot-ordered feature buffer yperm.
__launch_bounds__(256)
__global__ void fill_perm(int* __restrict__ grid, const int* __restrict__ blockoff,
                          int* __restrict__ perm){
  int b = blockIdx.x, t = threadIdx.x;
  int w = t >> 6, lane = t & 63;
  __shared__ int wcnt[4];
  __shared__ int carry;
  if(t == 0) carry = 0;
  __syncthreads();
  int base = blockoff[b];
  for(int p = 0; p < 4; p++){
    int v = b*1024 + p*256 + t;
    int s = grid[v];
    bool act = (s >= 0);
    u64 bal = __ballot(act);
    int pre = (int)__popcll(bal & ((1ull << lane) - 1ull));
    if(lane == 0) wcnt[w] = (int)__popcll(bal);
    __syncthreads();
    int woff = 0;
    for(int ww = 0; ww < w; ww++) woff += wcnt[ww];
    if(act){
      int slot = base + carry + woff + pre;
      perm[slot] = s;
      grid[v] = slot;                       // voxel -> slot remap
    }
    int tot = wcnt[0] + wcnt[1] + wcnt[2] + wcnt[3];
    __syncthreads();
    if(t == 0) carry += tot;
    __syncthreads();
  }
}

// ---------- rank[site] = slot (inverse perm) ----------
__launch_bounds__(256)
__global__ void rank_build(const int* __restrict__ perm, int* __restrict__ rank){
  int j = blockIdx.x*256 + threadIdx.x;
  if(j < N_SITES) rank[perm[j]] = j;
}

// ---------- pad perm slots; zero the sentinel feature row ----------
__global__ void pad_perm(int* __restrict__ perm, u32* __restrict__ yzero){
  int t = threadIdx.x;
  if(t < NSLOT - N_SITES) perm[N_SITES + t] = perm[0];
  if(t < 16) yzero[t] = 0;                    // 64 B zero row at ZROW
}

// ---------- pack W f32 [125][cin][cout] into bf16 32x32x16 B-fragment order ----------
// wf element index i = ((off*2 + half)*64 + lane)*8 + j
// value = W[off][k][n], k = half*16 + (lane>>5)*8 + j, n = lane&31
__launch_bounds__(256)
__global__ void prep_wfrag(const float* __restrict__ w, u16* __restrict__ wf){
  int i = blockIdx.x*256 + threadIdx.x;
  if(i >= KVOL*2*64*8) return;
  int j    = i & 7;
  int lane = (i >> 3) & 63;
  int half = (i >> 9) & 1;
  int off  = i >> 10;
  int k = half*16 + ((lane >> 5) << 3) + j;
  int n = lane & 31;
  wf[i] = f2bf(w[off*1024 + k*32 + n]);
}

// ---------- submanifold sparse conv via MFMA gather-GEMM ----------
// v6 = v5 + slot-ordered features (THE change): grid probes return voxel-order
// slots; yperm rows are in slot order, so a wave's gathers per dz-plane hit a
// ~6-10KB contiguous-ish window -> L1-resident, ~10x less L2 traffic (v5 was
// at ~24 TB/s of random 64B L2 requests, the scattered-access ceiling).
__launch_bounds__(256)
__global__ void conv_mfma(const u16* __restrict__ y, const int4* __restrict__ coords,
                          const u16* __restrict__ wf, const int* __restrict__ grid,
                          const int* __restrict__ perm, float* __restrict__ out){
  const char* __restrict__ yc  = (const char*)y;
  const char* __restrict__ gc  = (const char*)grid;
  __shared__ v8s swf[3200];                 // 51,200 B: [25 off][2 half][64 lane] x 16B

  int t = threadIdx.x;
  int l = t & 63;
  int r31 = l & 31;
  int h = l >> 5;
  u32 koff = (u32)h << 4;          // A k-half byte offset within a 64B row

  // bijective XCD swizzle
  int nwg = gridDim.x, bid = blockIdx.x;
  int xcd = bid & 7, rank = bid >> 3;
  int q8 = nwg >> 3, r8 = nwg & 7;
  int swz = (xcd < r8 ? xcd*(q8+1) : r8*(q8+1) + (xcd - r8)*q8) + rank;

  int slot = swz*256 + t;
  int p = perm[slot];
  int4 c = coords[p];                       // (b, z, y, x)
  int Z = c.y, Y = c.z, X = c.w;
  int base = ((c.x*DD + Z)*HHH + Y)*WWW + X;

  // per-group A-row site parameters (one-time redistribution)
  int b0 = __shfl(base, r31);
  int b1 = __shfl(base, 32 + r31);
  int x0 = __shfl(X, r31),  x1 = __shfl(X, 32 + r31);
  int y0 = __shfl(Y, r31),  y1 = __shfl(Y, 32 + r31);
  int z0 = __shfl(Z, r31),  z1 = __shfl(Z, 32 + r31);

  bool okx0[5], okx1[5], oky0[5], oky1[5];
  #pragma unroll
  for(int k = 0; k < 5; k++){
    okx0[k] = (u32)(x0 + k - 2) < WWW;
    okx1[k] = (u32)(x1 + k - 2) < WWW;
    oky0[k] = (u32)(y0 + k - 2) < HHH;
    oky1[k] = (u32)(y1 + k - 2) < HHH;
  }

  v16f acc0, acc1;
  #pragma unroll
  for(int i = 0; i < 16; i++){ acc0[i] = 0.f; acc1[i] = 0.f; }

  const int HW = HHH*WWW;
  const uint4* __restrict__ wfv = (const uint4*)wf;

  #pragma unroll 1
  for(int dz = -2; dz <= 2; dz++){
    bool okz0 = (u32)(z0 + dz) < DD;
    bool okz1 = (u32)(z1 + dz) < DD;
    int pb0 = b0 + dz*HW, pb1 = b1 + dz*HW;

    __syncthreads();                        // prior plane's LDS reads complete
    // ---- stage this plane's 25 weight-fragment pairs into LDS ----
    {
      u32 pbase = (u32)((dz + 2) * 3200);   // in 16B chunks
      #pragma unroll
      for(int it = 0; it < 13; it++){
        int ch = it*256 + t;
        if(ch < 3200){
          uint4 v = wfv[pbase + ch];
          *(uint4*)&swf[ch] = v;
        }
      }
    }

    // ---- probe phase: 50 independent sentinel-masked loads in flight ----
    int nv0[25], nv1[25];
    #pragma unroll
    for(int r = 0; r < 5; r++){
      bool zy0 = okz0 && oky0[r];
      bool zy1 = okz1 && oky1[r];
      #pragma unroll
      for(int k = 0; k < 5; k++){
        int d = (r-2)*WWW + (k-2);
        u32 a0 = (zy0 && okx0[k]) ? (u32)(pb0 + d) : (u32)NVOX;
        u32 a1 = (zy1 && okx1[k]) ? (u32)(pb1 + d) : (u32)NVOX;
        nv0[r*5+k] = *(const int*)(gc + a0*4u);   // grid[NVOX] = -1 sentinel
        nv1[r*5+k] = *(const int*)(gc + a1*4u);
      }
    }
    asm volatile("" ::: "memory");          // pin probes (defeat load-sinking)
    __syncthreads();                        // weights staged

    // ---- process phase: branch-free straight line ----
    #pragma unroll
    for(int o = 0; o < 25; o++){
      v8s wb0 = swf[o*128 + l];             // ds_read_b128
      v8s wb1 = swf[o*128 + 64 + l];

      int n0 = nv0[o];
      u32 rw0 = (u32)n0 < (u32)ZROW ? (u32)n0 : (u32)ZROW;   // invalid -> zero row
      u32 ya0 = (rw0 << 6) + koff;
      v8s a00 = *(const v8s*)(yc + ya0);
      v8s a01 = *(const v8s*)(yc + ya0 + 32u);
      acc0 = __builtin_amdgcn_mfma_f32_32x32x16_bf16(a00, wb0, acc0, 0, 0, 0);
      acc0 = __builtin_amdgcn_mfma_f32_32x32x16_bf16(a01, wb1, acc0, 0, 0, 0);

      int n1 = nv1[o];
      u32 rw1 = (u32)n1 < (u32)ZROW ? (u32)n1 : (u32)ZROW;
      u32 ya1 = (rw1 << 6) + koff;
      v8s a10 = *(const v8s*)(yc + ya1);
      v8s a11 = *(const v8s*)(yc + ya1 + 32u);
      acc1 = __builtin_amdgcn_mfma_f32_32x32x16_bf16(a10, wb0, acc1, 0, 0, 0);
      acc1 = __builtin_amdgcn_mfma_f32_32x32x16_bf16(a11, wb1, acc1, 0, 0, 0);
    }
  }

  // epilogue: C/D layout col=lane&31, row=(reg&3)+8*(reg>>2)+4*(lane>>5)  [m74/m101]
  #pragma unroll
  for(int rg = 0; rg < 16; rg++){
    int row = (rg & 3) + ((rg >> 2) << 3) + (h << 2);
    int s0 = __shfl(p, row);
    int s1 = __shfl(p, 32 + row);
    out[(size_t)s0*32 + r31] = acc0[rg];
    out[(size_t)s1*32 + r31] = acc1[rg];
  }
}

extern "C" void kernel_launch(void* const* d_in, const int* in_sizes, int n_in,
                              void* d_out, int out_size, void* d_ws, size_t ws_size,
                              hipStream_t stream) {
  const float* feats  = (const float*)d_in[0];   // [N,32] f32
  const int4*  coords = (const int4*) d_in[1];   // [N,4] int32
  const float* gamma  = (const float*)d_in[2];   // [32] f32
  const float* beta   = (const float*)d_in[3];   // [32] f32
  const float* wght   = (const float*)d_in[4];   // [125,32,32] f32
  float* out = (float*)d_out;

  char* ws = (char*)d_ws;
  int*   grid     = (int*)  ws;                   // 33,554,496 B (NVOX+1 ints, padded)
  u16*   yperm    = (u16*)  (ws + 33554496);      // 32,000,064 B (500001 rows, SLOT order)
  u16*   wf       = (u16*)  (ws + 65554560);      //    256,000 B
  int*   perm     = (int*)  (ws + 65810560);      //  2,000,896 B
  int*   blockcnt = (int*)  (ws + 67811456);      //     32,768 B
  int*   blockoff = (int*)  (ws + 67844224);      //     32,768 B
  float* partial  = (float*)(ws + 67876992);      //    129,024 B
  float* ss       = (float*)(ws + 68006016);      //        256 B
  // total: 68,006,272 B
  // rank[] (2MB) lives in the FIRST 2MB of d_out: written by rank_build,
  // consumed by bn_apply_y, fully overwritten by conv_mfma afterwards.
  int* rank = (int*)d_out;

  hipMemsetAsync(grid, 0xFF, (size_t)NVOX*4 + 4, stream);   // grid = -1, incl. sentinel

  // ---- geometry chain first (perm/rank needed by bn_apply_y scatter) ----
  build_grid  <<<(N_SITES+255)/256, 256, 0, stream>>>(coords, grid);
  count_blocks<<<CNT_BLOCKS, 256, 0, stream>>>(grid, blockcnt);
  scan_blocks <<<1, 1024, 0, stream>>>(blockcnt, blockoff);
  fill_perm   <<<CNT_BLOCKS, 256, 0, stream>>>(grid, blockoff, perm);
  rank_build  <<<(N_SITES+255)/256, 256, 0, stream>>>(perm, rank);
  pad_perm    <<<1, 256, 0, stream>>>(perm, (u32*)(yperm + (size_t)ZROW*32));

  // ---- BN chain ----
  bn_reduce  <<<RED_BLOCKS, 256, 0, stream>>>(feats, partial);
  bn_finalize<<<1, 32, 0, stream>>>(partial, gamma, beta, ss, RED_BLOCKS);
  bn_apply_y <<<2048, 256, 0, stream>>>((const float4*)feats, ss, rank, (uint4*)yperm);

  prep_wfrag<<<(KVOL*2*64*8 + 255)/256, 256, 0, stream>>>(wght, wf);

  conv_mfma<<<NSLOT/256, 256, 0, stream>>>(yperm, coords, wf, grid, perm, out);
}

// Round 6
// 596.993 us; speedup vs baseline: 1.3216x; 1.0826x over previous
//
#include <hip/hip_runtime.h>

typedef unsigned short u16;
typedef unsigned int u32;
typedef unsigned long long u64;

#define N_SITES 500000
#define CIN 32
#define COUT 32
#define DD 128
#define HHH 128
#define WWW 128
#define KVOL 125
#define EPSV 1e-4f
#define NVOX (4*DD*HHH*WWW)           // 8,388,608 = 8192 * 1024
#define RED_BLOCKS 504
#define CNT_BLOCKS 8192
#define NSLOT 500224                  // 1954 * 256 (padded site slots)
#define ZROW  N_SITES                 // zero feature row index in yperm

typedef short v8s __attribute__((ext_vector_type(8)));
typedef float v16f __attribute__((ext_vector_type(16)));

// ---------- helpers ----------
__device__ __forceinline__ u16 f2bf(float f){
  union { float f; u32 i; } v; v.f = f;
  u32 r = v.i + 0x7fffu + ((v.i >> 16) & 1u);
  return (u16)(r >> 16);
}

// ---------- BN stage 1: per-block partial sums (f32 input) ----------
__launch_bounds__(256)
__global__ void bn_reduce(const float* __restrict__ x, float* __restrict__ partial){
  __shared__ float ssum[8][32], ssq[8][32];
  int tid = threadIdx.x;
  int c   = tid & 31;
  int row = tid >> 5;
  float s = 0.f, q = 0.f;
  for(int site = blockIdx.x*8 + row; site < N_SITES; site += gridDim.x*8){
    float f = x[(size_t)site*32 + c];
    s += f; q += f*f;
  }
  ssum[row][c] = s; ssq[row][c] = q;
  __syncthreads();
  if(tid < 32){
    float ts = 0.f, tq = 0.f;
    #pragma unroll
    for(int r = 0; r < 8; r++){ ts += ssum[r][tid]; tq += ssq[r][tid]; }
    partial[blockIdx.x*64 + tid]      = ts;
    partial[blockIdx.x*64 + 32 + tid] = tq;
  }
}

// ---------- BN finalize + perm pad + zero-row (fused; needs partial AND perm) ----------
__global__ void bn_finalize_pad(const float* __restrict__ partial, const float* __restrict__ gamma,
                                const float* __restrict__ beta, float* __restrict__ ss, int nblk,
                                int* __restrict__ perm, u32* __restrict__ yzero){
  int tid = threadIdx.x;
  if(tid < 32){
    float s = 0.f, q = 0.f;
    for(int b = 0; b < nblk; b++){
      s += partial[b*64 + tid];
      q += partial[b*64 + 32 + tid];
    }
    float mean = s / (float)N_SITES;
    float var  = q / (float)N_SITES - mean*mean;   // biased, matches reference
    float scale = gamma[tid] * rsqrtf(var + EPSV);
    ss[tid]      = scale;
    ss[32 + tid] = beta[tid] - mean*scale;
  }
  if(tid < NSLOT - N_SITES) perm[N_SITES + tid] = perm[0];
  if(tid < 16) yzero[tid] = 0;                    // 64 B zero row at ZROW
}

// ---------- y = bf16(relu(x*scale+shift)) scattered into SLOT order ----------
__launch_bounds__(256)
__global__ void bn_apply_y(const float4* __restrict__ xv, const float* __restrict__ ss,
                           const int* __restrict__ rank, uint4* __restrict__ yv){
  __shared__ float sc[64];
  int tid = threadIdx.x;
  if(tid < 64) sc[tid] = ss[tid];
  __syncthreads();
  const int total = N_SITES*CIN/8;            // 2,000,000 chunks of 8
  int stride = gridDim.x*256;
  for(int i = blockIdx.x*256 + tid; i < total; i += stride){
    int c0 = (i & 3) * 8;
    int slot = rank[i >> 2];
    float4 a = xv[2*i], b = xv[2*i+1];
    float f[8] = {a.x,a.y,a.z,a.w,b.x,b.y,b.z,b.w};
    #pragma unroll
    for(int j = 0; j < 8; j++) f[j] = fmaxf(f[j]*sc[c0+j] + sc[32+c0+j], 0.f);
    uint4 o;
    o.x = ((u32)f2bf(f[1])<<16) | f2bf(f[0]);
    o.y = ((u32)f2bf(f[3])<<16) | f2bf(f[2]);
    o.z = ((u32)f2bf(f[5])<<16) | f2bf(f[4]);
    o.w = ((u32)f2bf(f[7])<<16) | f2bf(f[6]);
    yv[slot*4 + (i & 3)] = o;
  }
}

// ---------- scatter site indices into dense voxel grid ----------
__launch_bounds__(256)
__global__ void build_grid(const int4* __restrict__ coords, int* __restrict__ grid){
  int i = blockIdx.x*256 + threadIdx.x;
  if(i >= N_SITES) return;
  int4 c = coords[i];  // (b, z, y, x)
  grid[((c.x*DD + c.y)*HHH + c.z)*WWW + c.w] = i;
}

// ---------- per-1024-voxel-block active counts ----------
__launch_bounds__(256)
__global__ void count_blocks(const int* __restrict__ grid, int* __restrict__ blockcnt){
  int b = blockIdx.x, t = threadIdx.x;
  int cnt = 0;
  #pragma unroll
  for(int k = 0; k < 4; k++) cnt += (grid[b*1024 + k*256 + t] >= 0);
  #pragma unroll
  for(int o = 32; o > 0; o >>= 1) cnt += __shfl_down(cnt, o);
  __shared__ int wsum[4];
  if((t & 63) == 0) wsum[t >> 6] = cnt;
  __syncthreads();
  if(t == 0) blockcnt[b] = wsum[0] + wsum[1] + wsum[2] + wsum[3];
}

// ---------- exclusive prefix over 8192 block counts (one block) ----------
__launch_bounds__(1024)
__global__ void scan_blocks(const int* __restrict__ blockcnt, int* __restrict__ blockoff){
  __shared__ int s[1024];
  int t = threadIdx.x;
  int loc[8]; int v = 0;
  #pragma unroll
  for(int k = 0; k < 8; k++){ loc[k] = blockcnt[t*8 + k]; v += loc[k]; }
  s[t] = v; __syncthreads();
  for(int o = 1; o < 1024; o <<= 1){
    int add = (t >= o) ? s[t - o] : 0;
    __syncthreads();
    s[t] += add;
    __syncthreads();
  }
  int base = s[t] - v;
  #pragma unroll
  for(int k = 0; k < 8; k++){ blockoff[t*8 + k] = base; base += loc[k]; }
}

// ---------- ordered compaction: perm[slot]=site, rank[site]=slot, grid[v]:=slot ----------
__launch_bounds__(256)
__global__ void fill_perm(int* __restrict__ grid, const int* __restrict__ blockoff,
                          int* __restrict__ perm, int* __restrict__ rank){
  int b = blockIdx.x, t = threadIdx.x;
  int w = t >> 6, lane = t & 63;
  __shared__ int wcnt[4];
  __shared__ int carry;
  if(t == 0) carry = 0;
  __syncthreads();
  int base = blockoff[b];
  for(int p = 0; p < 4; p++){
    int v = b*1024 + p*256 + t;
    int s = grid[v];
    bool act = (s >= 0);
    u64 bal = __ballot(act);
    int pre = (int)__popcll(bal & ((1ull << lane) - 1ull));
    if(lane == 0) wcnt[w] = (int)__popcll(bal);
    __syncthreads();
    int woff = 0;
    for(int ww = 0; ww < w; ww++) woff += wcnt[ww];
    if(act){
      int slot = base + carry + woff + pre;
      perm[slot] = s;
      rank[s] = slot;
      grid[v] = slot;                       // voxel -> slot remap
    }
    int tot = wcnt[0] + wcnt[1] + wcnt[2] + wcnt[3];
    __syncthreads();
    if(t == 0) carry += tot;
    __syncthreads();
  }
}

// ---------- pack W f32 [125][cin][cout] into bf16 32x32x16 B-fragment order ----------
// wf element index i = ((off*2 + half)*64 + lane)*8 + j
// value = W[off][k][n], k = half*16 + (lane>>5)*8 + j, n = lane&31
__launch_bounds__(256)
__global__ void prep_wfrag(const float* __restrict__ w, u16* __restrict__ wf){
  int i = blockIdx.x*256 + threadIdx.x;
  if(i >= KVOL*2*64*8) return;
  int j    = i & 7;
  int lane = (i >> 3) & 63;
  int half = (i >> 9) & 1;
  int off  = i >> 10;
  int k = half*16 + ((lane >> 5) << 3) + j;
  int n = lane & 31;
  wf[i] = f2bf(w[off*1024 + k*32 + n]);
}

// ---------- submanifold sparse conv via MFMA gather-GEMM ----------
// v7 = v6 + row-batched gather pipeline: per dy-row, issue ALL 20 A-gathers
// (5 offsets x 2 groups x 2 frags), fence; issue next row's 10 probes
// (latency hides under this row's MFMAs), fence; then process the 5 offsets.
// Compiler emits counted vmcnt waits, so MFMA group k waits only its own 4
// loads while 16+ stay in flight -> ~5x per-wave MLP (v6's VGPR=68 proved
// gathers were sunk to point-of-use, one latency exposed per offset).
// No VGPR cap, fr[20] fully-unrolled static indexing (no spill risk a la v4).
__launch_bounds__(256)
__global__ void conv_mfma(const u16* __restrict__ y, const int4* __restrict__ coords,
                          const u16* __restrict__ wf, const int* __restrict__ grid,
                          const int* __restrict__ perm, float* __restrict__ out){
  const char* __restrict__ yc  = (const char*)y;
  const char* __restrict__ gc  = (const char*)grid;
  __shared__ v8s swf[3200];                 // 51,200 B: [25 off][2 half][64 lane] x 16B

  int t = threadIdx.x;
  int l = t & 63;
  int r31 = l & 31;
  int h = l >> 5;
  u32 koff = (u32)h << 4;          // A k-half byte offset within a 64B row

  // bijective XCD swizzle
  int nwg = gridDim.x, bid = blockIdx.x;
  int xcd = bid & 7, rk = bid >> 3;
  int q8 = nwg >> 3, r8 = nwg & 7;
  int swz = (xcd < r8 ? xcd*(q8+1) : r8*(q8+1) + (xcd - r8)*q8) + rk;

  int slot = swz*256 + t;
  int p = perm[slot];
  int4 c = coords[p];                       // (b, z, y, x)
  int Z = c.y, Y = c.z, X = c.w;
  int base = ((c.x*DD + Z)*HHH + Y)*WWW + X;

  // per-group A-row site parameters (one-time redistribution)
  int b0 = __shfl(base, r31);
  int b1 = __shfl(base, 32 + r31);
  int x0 = __shfl(X, r31),  x1 = __shfl(X, 32 + r31);
  int y0 = __shfl(Y, r31),  y1 = __shfl(Y, 32 + r31);
  int z0 = __shfl(Z, r31),  z1 = __shfl(Z, 32 + r31);

  bool okx0[5], okx1[5], oky0[5], oky1[5];
  #pragma unroll
  for(int k = 0; k < 5; k++){
    okx0[k] = (u32)(x0 + k - 2) < WWW;
    okx1[k] = (u32)(x1 + k - 2) < WWW;
    oky0[k] = (u32)(y0 + k - 2) < HHH;
    oky1[k] = (u32)(y1 + k - 2) < HHH;
  }

  v16f acc0, acc1;
  #pragma unroll
  for(int i = 0; i < 16; i++){ acc0[i] = 0.f; acc1[i] = 0.f; }

  const int HW = HHH*WWW;
  const uint4* __restrict__ wfv = (const uint4*)wf;

// probe row rr (both groups, 10 sentinel-masked loads)
#define PROBE_ROW(rr) { \
    bool zy0 = okz0 && oky0[rr]; \
    bool zy1 = okz1 && oky1[rr]; \
    _Pragma("unroll") \
    for(int k = 0; k < 5; k++){ \
      int d = ((rr)-2)*WWW + (k-2); \
      u32 a0 = (zy0 && okx0[k]) ? (u32)(pb0 + d) : (u32)NVOX; \
      u32 a1 = (zy1 && okx1[k]) ? (u32)(pb1 + d) : (u32)NVOX; \
      nv[rr][k]     = *(const int*)(gc + a0*4u); \
      nv[rr][5 + k] = *(const int*)(gc + a1*4u); \
    } }

  #pragma unroll 1
  for(int dz = -2; dz <= 2; dz++){
    bool okz0 = (u32)(z0 + dz) < DD;
    bool okz1 = (u32)(z1 + dz) < DD;
    int pb0 = b0 + dz*HW, pb1 = b1 + dz*HW;

    int nv[5][10];
    PROBE_ROW(0)                            // row-0 probes fly during staging
    asm volatile("" ::: "memory");

    __syncthreads();                        // prior plane's LDS reads complete
    // ---- stage this plane's 25 weight-fragment pairs into LDS ----
    {
      u32 pbase = (u32)((dz + 2) * 3200);   // in 16B chunks
      #pragma unroll
      for(int it = 0; it < 13; it++){
        int ch = it*256 + t;
        if(ch < 3200){
          uint4 v = wfv[pbase + ch];
          *(uint4*)&swf[ch] = v;
        }
      }
    }
    __syncthreads();                        // weights staged

    // ---- row-pipelined gather + process ----
    #pragma unroll
    for(int r = 0; r < 5; r++){
      // issue all 20 A-gathers for this row
      v8s fr[20];
      #pragma unroll
      for(int k = 0; k < 5; k++){
        u32 n0 = (u32)nv[r][k],   n1 = (u32)nv[r][5+k];
        u32 rw0 = n0 < (u32)ZROW ? n0 : (u32)ZROW;   // invalid -> zero row
        u32 rw1 = n1 < (u32)ZROW ? n1 : (u32)ZROW;
        u32 ya0 = (rw0 << 6) + koff;
        u32 ya1 = (rw1 << 6) + koff;
        fr[k*4+0] = *(const v8s*)(yc + ya0);
        fr[k*4+1] = *(const v8s*)(yc + ya0 + 32u);
        fr[k*4+2] = *(const v8s*)(yc + ya1);
        fr[k*4+3] = *(const v8s*)(yc + ya1 + 32u);
      }
      asm volatile("" ::: "memory");        // pin: 20 gathers issued first
      if(r < 4){
        PROBE_ROW(r+1)                      // next row's probes hide under MFMAs
        asm volatile("" ::: "memory");
      }
      // process the row: weights from LDS, 20 MFMAs
      #pragma unroll
      for(int k = 0; k < 5; k++){
        int o = r*5 + k;
        v8s wb0 = swf[o*128 + l];           // ds_read_b128
        v8s wb1 = swf[o*128 + 64 + l];
        acc0 = __builtin_amdgcn_mfma_f32_32x32x16_bf16(fr[k*4+0], wb0, acc0, 0, 0, 0);
        acc0 = __builtin_amdgcn_mfma_f32_32x32x16_bf16(fr[k*4+1], wb1, acc0, 0, 0, 0);
        acc1 = __builtin_amdgcn_mfma_f32_32x32x16_bf16(fr[k*4+2], wb0, acc1, 0, 0, 0);
        acc1 = __builtin_amdgcn_mfma_f32_32x32x16_bf16(fr[k*4+3], wb1, acc1, 0, 0, 0);
      }
    }
  }
#undef PROBE_ROW

  // epilogue: C/D layout col=lane&31, row=(reg&3)+8*(reg>>2)+4*(lane>>5)  [m74/m101]
  #pragma unroll
  for(int rg = 0; rg < 16; rg++){
    int row = (rg & 3) + ((rg >> 2) << 3) + (h << 2);
    int s0 = __shfl(p, row);
    int s1 = __shfl(p, 32 + row);
    out[(size_t)s0*32 + r31] = acc0[rg];
    out[(size_t)s1*32 + r31] = acc1[rg];
  }
}

extern "C" void kernel_launch(void* const* d_in, const int* in_sizes, int n_in,
                              void* d_out, int out_size, void* d_ws, size_t ws_size,
                              hipStream_t stream) {
  const float* feats  = (const float*)d_in[0];   // [N,32] f32
  const int4*  coords = (const int4*) d_in[1];   // [N,4] int32
  const float* gamma  = (const float*)d_in[2];   // [32] f32
  const float* beta   = (const float*)d_in[3];   // [32] f32
  const float* wght   = (const float*)d_in[4];   // [125,32,32] f32
  float* out = (float*)d_out;

  char* ws = (char*)d_ws;
  int*   grid     = (int*)  ws;                   // 33,554,496 B (NVOX+1 ints, padded)
  u16*   yperm    = (u16*)  (ws + 33554496);      // 32,000,064 B (500001 rows, SLOT order)
  u16*   wf       = (u16*)  (ws + 65554560);      //    256,000 B
  int*   perm     = (int*)  (ws + 65810560);      //  2,000,896 B
  int*   blockcnt = (int*)  (ws + 67811456);      //     32,768 B
  int*   blockoff = (int*)  (ws + 67844224);      //     32,768 B
  float* partial  = (float*)(ws + 67876992);      //    129,024 B
  float* ss       = (float*)(ws + 68006016);      //        256 B
  // total: 68,006,272 B
  // rank[] (2MB) lives in the FIRST 2MB of d_out: written by fill_perm,
  // consumed by bn_apply_y, fully overwritten by conv_mfma afterwards.
  int* rank = (int*)d_out;

  hipMemsetAsync(grid, 0xFF, (size_t)NVOX*4 + 4, stream);   // grid = -1, incl. sentinel

  // ---- geometry chain (perm/rank needed by bn_apply_y scatter) ----
  build_grid  <<<(N_SITES+255)/256, 256, 0, stream>>>(coords, grid);
  count_blocks<<<CNT_BLOCKS, 256, 0, stream>>>(grid, blockcnt);
  scan_blocks <<<1, 1024, 0, stream>>>(blockcnt, blockoff);
  fill_perm   <<<CNT_BLOCKS, 256, 0, stream>>>(grid, blockoff, perm, rank);

  // ---- BN chain ----
  bn_reduce      <<<RED_BLOCKS, 256, 0, stream>>>(feats, partial);
  bn_finalize_pad<<<1, 256, 0, stream>>>(partial, gamma, beta, ss, RED_BLOCKS,
                                         perm, (u32*)(yperm + (size_t)ZROW*32));
  bn_apply_y <<<2048, 256, 0, stream>>>((const float4*)feats, ss, rank, (uint4*)yperm);

  prep_wfrag<<<(KVOL*2*64*8 + 255)/256, 256, 0, stream>>>(wght, wf);

  conv_mfma<<<NSLOT/256, 256, 0, stream>>>(yperm, coords, wf, grid, perm, out);
}

// Round 7
// 537.175 us; speedup vs baseline: 1.4688x; 1.1114x over previous
//
#include <hip/hip_runtime.h>

typedef unsigned short u16;
typedef unsigned int u32;
typedef unsigned long long u64;

#define N_SITES 500000
#define CIN 32
#define COUT 32
#define DD 128
#define HHH 128
#define WWW 128
#define KVOL 125
#define EPSV 1e-4f
#define NVOX (4*DD*HHH*WWW)           // 8,388,608 = 8192 * 1024
#define RED_BLOCKS 504
#define CNT_BLOCKS 8192
#define NSLOT 500224                  // 1954 * 256 (padded site slots)
#define ZROW  N_SITES                 // zero feature row index in yperm
#define SENTI (NVOX+4)                // sentinel window start (post-pad, all -1)

typedef short v8s __attribute__((ext_vector_type(8)));
typedef float v16f __attribute__((ext_vector_type(16)));

// ---------- helpers ----------
__device__ __forceinline__ u16 f2bf(float f){
  union { float f; u32 i; } v; v.f = f;
  u32 r = v.i + 0x7fffu + ((v.i >> 16) & 1u);
  return (u16)(r >> 16);
}

// ---------- BN stage 1: per-block partial sums (f32 input) ----------
__launch_bounds__(256)
__global__ void bn_reduce(const float* __restrict__ x, float* __restrict__ partial){
  __shared__ float ssum[8][32], ssq[8][32];
  int tid = threadIdx.x;
  int c   = tid & 31;
  int row = tid >> 5;
  float s = 0.f, q = 0.f;
  for(int site = blockIdx.x*8 + row; site < N_SITES; site += gridDim.x*8){
    float f = x[(size_t)site*32 + c];
    s += f; q += f*f;
  }
  ssum[row][c] = s; ssq[row][c] = q;
  __syncthreads();
  if(tid < 32){
    float ts = 0.f, tq = 0.f;
    #pragma unroll
    for(int r = 0; r < 8; r++){ ts += ssum[r][tid]; tq += ssq[r][tid]; }
    partial[blockIdx.x*64 + tid]      = ts;
    partial[blockIdx.x*64 + 32 + tid] = tq;
  }
}

// ---------- BN finalize + perm pad + zero-row (fused) ----------
__global__ void bn_finalize_pad(const float* __restrict__ partial, const float* __restrict__ gamma,
                                const float* __restrict__ beta, float* __restrict__ ss, int nblk,
                                int* __restrict__ perm, u32* __restrict__ yzero){
  int tid = threadIdx.x;
  if(tid < 32){
    float s = 0.f, q = 0.f;
    for(int b = 0; b < nblk; b++){
      s += partial[b*64 + tid];
      q += partial[b*64 + 32 + tid];
    }
    float mean = s / (float)N_SITES;
    float var  = q / (float)N_SITES - mean*mean;   // biased, matches reference
    float scale = gamma[tid] * rsqrtf(var + EPSV);
    ss[tid]      = scale;
    ss[32 + tid] = beta[tid] - mean*scale;
  }
  if(tid < NSLOT - N_SITES) perm[N_SITES + tid] = perm[0];
  if(tid < 16) yzero[tid] = 0;                    // 64 B zero row at ZROW
}

// ---------- y = bf16(relu(x*scale+shift)) scattered into SLOT order ----------
__launch_bounds__(256)
__global__ void bn_apply_y(const float4* __restrict__ xv, const float* __restrict__ ss,
                           const int* __restrict__ rank, uint4* __restrict__ yv){
  __shared__ float sc[64];
  int tid = threadIdx.x;
  if(tid < 64) sc[tid] = ss[tid];
  __syncthreads();
  const int total = N_SITES*CIN/8;            // 2,000,000 chunks of 8
  int stride = gridDim.x*256;
  for(int i = blockIdx.x*256 + tid; i < total; i += stride){
    int c0 = (i & 3) * 8;
    int slot = rank[i >> 2];
    float4 a = xv[2*i], b = xv[2*i+1];
    float f[8] = {a.x,a.y,a.z,a.w,b.x,b.y,b.z,b.w};
    #pragma unroll
    for(int j = 0; j < 8; j++) f[j] = fmaxf(f[j]*sc[c0+j] + sc[32+c0+j], 0.f);
    uint4 o;
    o.x = ((u32)f2bf(f[1])<<16) | f2bf(f[0]);
    o.y = ((u32)f2bf(f[3])<<16) | f2bf(f[2]);
    o.z = ((u32)f2bf(f[5])<<16) | f2bf(f[4]);
    o.w = ((u32)f2bf(f[7])<<16) | f2bf(f[6]);
    yv[slot*4 + (i & 3)] = o;
  }
}

// ---------- scatter site indices into dense voxel grid ----------
__launch_bounds__(256)
__global__ void build_grid(const int4* __restrict__ coords, int* __restrict__ grid){
  int i = blockIdx.x*256 + threadIdx.x;
  if(i >= N_SITES) return;
  int4 c = coords[i];  // (b, z, y, x)
  grid[((c.x*DD + c.y)*HHH + c.z)*WWW + c.w] = i;
}

// ---------- per-1024-voxel-block active counts ----------
__launch_bounds__(256)
__global__ void count_blocks(const int* __restrict__ grid, int* __restrict__ blockcnt){
  int b = blockIdx.x, t = threadIdx.x;
  int cnt = 0;
  #pragma unroll
  for(int k = 0; k < 4; k++) cnt += (grid[b*1024 + k*256 + t] >= 0);
  #pragma unroll
  for(int o = 32; o > 0; o >>= 1) cnt += __shfl_down(cnt, o);
  __shared__ int wsum[4];
  if((t & 63) == 0) wsum[t >> 6] = cnt;
  __syncthreads();
  if(t == 0) blockcnt[b] = wsum[0] + wsum[1] + wsum[2] + wsum[3];
}

// ---------- exclusive prefix over 8192 block counts (one block) ----------
__launch_bounds__(1024)
__global__ void scan_blocks(const int* __restrict__ blockcnt, int* __restrict__ blockoff){
  __shared__ int s[1024];
  int t = threadIdx.x;
  int loc[8]; int v = 0;
  #pragma unroll
  for(int k = 0; k < 8; k++){ loc[k] = blockcnt[t*8 + k]; v += loc[k]; }
  s[t] = v; __syncthreads();
  for(int o = 1; o < 1024; o <<= 1){
    int add = (t >= o) ? s[t - o] : 0;
    __syncthreads();
    s[t] += add;
    __syncthreads();
  }
  int base = s[t] - v;
  #pragma unroll
  for(int k = 0; k < 8; k++){ blockoff[t*8 + k] = base; base += loc[k]; }
}

// ---------- ordered compaction: perm[slot]=site, rank[site]=slot, grid[v]:=slot ----------
__launch_bounds__(256)
__global__ void fill_perm(int* __restrict__ grid, const int* __restrict__ blockoff,
                          int* __restrict__ perm, int* __restrict__ rank){
  int b = blockIdx.x, t = threadIdx.x;
  int w = t >> 6, lane = t & 63;
  __shared__ int wcnt[4];
  __shared__ int carry;
  if(t == 0) carry = 0;
  __syncthreads();
  int base = blockoff[b];
  for(int p = 0; p < 4; p++){
    int v = b*1024 + p*256 + t;
    int s = grid[v];
    bool act = (s >= 0);
    u64 bal = __ballot(act);
    int pre = (int)__popcll(bal & ((1ull << lane) - 1ull));
    if(lane == 0) wcnt[w] = (int)__popcll(bal);
    __syncthreads();
    int woff = 0;
    for(int ww = 0; ww < w; ww++) woff += wcnt[ww];
    if(act){
      int slot = base + carry + woff + pre;
      perm[slot] = s;
      rank[s] = slot;
      grid[v] = slot;                       // voxel -> slot remap
    }
    int tot = wcnt[0] + wcnt[1] + wcnt[2] + wcnt[3];
    __syncthreads();
    if(t == 0) carry += tot;
    __syncthreads();
  }
}

// ---------- pack W f32 [125][cin][cout] into bf16 32x32x16 B-fragment order ----------
// wf element index i = ((off*2 + half)*64 + lane)*8 + j
// value = W[off][k][n], k = half*16 + (lane>>5)*8 + j, n = lane&31
__launch_bounds__(256)
__global__ void prep_wfrag(const float* __restrict__ w, u16* __restrict__ wf){
  int i = blockIdx.x*256 + threadIdx.x;
  if(i >= KVOL*2*64*8) return;
  int j    = i & 7;
  int lane = (i >> 3) & 63;
  int half = (i >> 9) & 1;
  int off  = i >> 10;
  int k = half*16 + ((lane >> 5) << 3) + j;
  int n = lane & 31;
  wf[i] = f2bf(w[off*1024 + k*32 + n]);
}

// ---------- submanifold sparse conv via MFMA gather-GEMM ----------
// v8 = v7 + vectorized window probes: per (row,group) TWO int4 loads cover
// the aligned 8-int window around the 5 dx-neighbors (probe insts/plane
// 50 -> 20); extraction (3-cndmask tree, v4-verified) deferred to the
// consuming row so raw windows ride in registers across the MFMA block.
// At 6% density gathers mostly coalesce onto the zero-row line; the scalar
// probe stream was the largest L1-tag consumer (~12k line-touches/wave).
__launch_bounds__(256)
__global__ void conv_mfma(const u16* __restrict__ y, const int4* __restrict__ coords,
                          const u16* __restrict__ wf, const int* __restrict__ gridp,
                          const int* __restrict__ perm, float* __restrict__ out){
  const char* __restrict__ yc  = (const char*)y;
  const char* __restrict__ gcp = (const char*)gridp;
  __shared__ v8s swf[3200];                 // 51,200 B: [25 off][2 half][64 lane] x 16B

  int t = threadIdx.x;
  int l = t & 63;
  int r31 = l & 31;
  int h = l >> 5;
  u32 koff = (u32)h << 4;          // A k-half byte offset within a 64B row

  // bijective XCD swizzle
  int nwg = gridDim.x, bid = blockIdx.x;
  int xcd = bid & 7, rk = bid >> 3;
  int q8 = nwg >> 3, r8 = nwg & 7;
  int swz = (xcd < r8 ? xcd*(q8+1) : r8*(q8+1) + (xcd - r8)*q8) + rk;

  int slot = swz*256 + t;
  int p = perm[slot];
  int4 c = coords[p];                       // (b, z, y, x)
  int Z = c.y, Y = c.z, X = c.w;
  int base = ((c.x*DD + Z)*HHH + Y)*WWW + X;

  // per-group A-row site parameters (one-time redistribution)
  int b0 = __shfl(base, r31);
  int b1 = __shfl(base, 32 + r31);
  int x0 = __shfl(X, r31),  x1 = __shfl(X, 32 + r31);
  int y0 = __shfl(Y, r31),  y1 = __shfl(Y, 32 + r31);
  int z0 = __shfl(Z, r31),  z1 = __shfl(Z, 32 + r31);

  bool okx0[5], okx1[5], oky0[5], oky1[5];
  #pragma unroll
  for(int k = 0; k < 5; k++){
    okx0[k] = (u32)(x0 + k - 2) < WWW;
    okx1[k] = (u32)(x1 + k - 2) < WWW;
    oky0[k] = (u32)(y0 + k - 2) < HHH;
    oky1[k] = (u32)(y1 + k - 2) < HHH;
  }

  v16f acc0, acc1;
  #pragma unroll
  for(int i = 0; i < 16; i++){ acc0[i] = 0.f; acc1[i] = 0.f; }

  const int HW = HHH*WWW;
  const uint4* __restrict__ wfv = (const uint4*)wf;

// issue the 4 window loads for row rr (both groups); raw regs stay in flight
#define PROBE_WIN(rr) { \
    bool zy0 = okz0 && oky0[rr]; \
    bool zy1 = okz1 && oky1[rr]; \
    int st0 = zy0 ? (pb0 + ((rr)-2)*WWW - 2) : SENTI; \
    int st1 = zy1 ? (pb1 + ((rr)-2)*WWW - 2) : SENTI; \
    int al0 = st0 & ~3, al1 = st1 & ~3; \
    sh0 = st0 - al0; sh1 = st1 - al1; \
    rA0 = *(const int4*)(gcp + (long)al0*4); \
    rA1 = *(const int4*)(gcp + (long)al0*4 + 16); \
    rB0 = *(const int4*)(gcp + (long)al1*4); \
    rB1 = *(const int4*)(gcp + (long)al1*4 + 16); \
  }

// extract 5 dx values per group from the raw windows (v4-verified tree)
#define EXTRACT(rr) { \
    int e0[8] = {rA0.x,rA0.y,rA0.z,rA0.w,rA1.x,rA1.y,rA1.z,rA1.w}; \
    int e1[8] = {rB0.x,rB0.y,rB0.z,rB0.w,rB1.x,rB1.y,rB1.z,rB1.w}; \
    bool sa2 = (sh0 & 2) != 0, sa1 = (sh0 & 1) != 0; \
    bool sb2 = (sh1 & 2) != 0, sb1 = (sh1 & 1) != 0; \
    _Pragma("unroll") \
    for(int k = 0; k < 5; k++){ \
      int t0 = sa2 ? e0[k+2] : e0[k]; \
      int t1 = sa2 ? e0[k+3] : e0[k+1]; \
      nvA[k] = okx0[k] ? (sa1 ? t1 : t0) : -1; \
      int u0 = sb2 ? e1[k+2] : e1[k]; \
      int u1 = sb2 ? e1[k+3] : e1[k+1]; \
      nvB[k] = okx1[k] ? (sb1 ? u1 : u0) : -1; \
    } \
  }

  #pragma unroll 1
  for(int dz = -2; dz <= 2; dz++){
    bool okz0 = (u32)(z0 + dz) < DD;
    bool okz1 = (u32)(z1 + dz) < DD;
    int pb0 = b0 + dz*HW, pb1 = b1 + dz*HW;

    int4 rA0, rA1, rB0, rB1;
    int sh0, sh1;
    PROBE_WIN(0)                            // row-0 windows fly during staging
    asm volatile("" ::: "memory");

    __syncthreads();                        // prior plane's LDS reads complete
    // ---- stage this plane's 25 weight-fragment pairs into LDS ----
    {
      u32 pbase = (u32)((dz + 2) * 3200);   // in 16B chunks
      #pragma unroll
      for(int it = 0; it < 13; it++){
        int ch = it*256 + t;
        if(ch < 3200){
          uint4 v = wfv[pbase + ch];
          *(uint4*)&swf[ch] = v;
        }
      }
    }
    __syncthreads();                        // weights staged

    // ---- row-pipelined: extract -> 20 gathers -> next-row windows -> MFMAs ----
    #pragma unroll
    for(int r = 0; r < 5; r++){
      int nvA[5], nvB[5];
      EXTRACT(r)
      v8s fr[20];
      #pragma unroll
      for(int k = 0; k < 5; k++){
        u32 n0 = (u32)nvA[k], n1 = (u32)nvB[k];
        u32 rw0 = n0 < (u32)ZROW ? n0 : (u32)ZROW;   // invalid -> zero row
        u32 rw1 = n1 < (u32)ZROW ? n1 : (u32)ZROW;
        u32 ya0 = (rw0 << 6) + koff;
        u32 ya1 = (rw1 << 6) + koff;
        fr[k*4+0] = *(const v8s*)(yc + ya0);
        fr[k*4+1] = *(const v8s*)(yc + ya0 + 32u);
        fr[k*4+2] = *(const v8s*)(yc + ya1);
        fr[k*4+3] = *(const v8s*)(yc + ya1 + 32u);
      }
      asm volatile("" ::: "memory");        // pin: 20 gathers issued first
      if(r < 4){
        PROBE_WIN(r+1)                      // next row's windows hide under MFMAs
        asm volatile("" ::: "memory");
      }
      // process the row: weights from LDS, 20 MFMAs
      #pragma unroll
      for(int k = 0; k < 5; k++){
        int o = r*5 + k;
        v8s wb0 = swf[o*128 + l];           // ds_read_b128
        v8s wb1 = swf[o*128 + 64 + l];
        acc0 = __builtin_amdgcn_mfma_f32_32x32x16_bf16(fr[k*4+0], wb0, acc0, 0, 0, 0);
        acc0 = __builtin_amdgcn_mfma_f32_32x32x16_bf16(fr[k*4+1], wb1, acc0, 0, 0, 0);
        acc1 = __builtin_amdgcn_mfma_f32_32x32x16_bf16(fr[k*4+2], wb0, acc1, 0, 0, 0);
        acc1 = __builtin_amdgcn_mfma_f32_32x32x16_bf16(fr[k*4+3], wb1, acc1, 0, 0, 0);
      }
    }
  }
#undef PROBE_WIN
#undef EXTRACT

  // epilogue: C/D layout col=lane&31, row=(reg&3)+8*(reg>>2)+4*(lane>>5)  [m74/m101]
  #pragma unroll
  for(int rg = 0; rg < 16; rg++){
    int row = (rg & 3) + ((rg >> 2) << 3) + (h << 2);
    int s0 = __shfl(p, row);
    int s1 = __shfl(p, 32 + row);
    out[(size_t)s0*32 + r31] = acc0[rg];
    out[(size_t)s1*32 + r31] = acc1[rg];
  }
}

extern "C" void kernel_launch(void* const* d_in, const int* in_sizes, int n_in,
                              void* d_out, int out_size, void* d_ws, size_t ws_size,
                              hipStream_t stream) {
  const float* feats  = (const float*)d_in[0];   // [N,32] f32
  const int4*  coords = (const int4*) d_in[1];   // [N,4] int32
  const float* gamma  = (const float*)d_in[2];   // [32] f32
  const float* beta   = (const float*)d_in[3];   // [32] f32
  const float* wght   = (const float*)d_in[4];   // [125,32,32] f32
  float* out = (float*)d_out;

  char* ws = (char*)d_ws;
  int*   grid_raw = (int*)  ws;                   // 33,554,560 B = (NVOX+32)*4 (8 pre + 24 post pad)
  int*   gridp    = grid_raw + 8;                 // usable grid [0, NVOX)
  u16*   yperm    = (u16*)  (ws + 33554560);      // 32,000,064 B (500001 rows, SLOT order)
  u16*   wf       = (u16*)  (ws + 65554624);      //    256,000 B
  int*   perm     = (int*)  (ws + 65810624);      //  2,000,896 B
  int*   blockcnt = (int*)  (ws + 67811520);      //     32,768 B
  int*   blockoff = (int*)  (ws + 67844288);      //     32,768 B
  float* partial  = (float*)(ws + 67877056);      //    129,024 B
  float* ss       = (float*)(ws + 68006080);      //        256 B
  // total: 68,006,336 B
  // rank[] (2MB) lives in the FIRST 2MB of d_out: written by fill_perm,
  // consumed by bn_apply_y, fully overwritten by conv_mfma afterwards.
  int* rank = (int*)d_out;

  hipMemsetAsync(grid_raw, 0xFF, (size_t)(NVOX+32)*4, stream);   // grid + pads = -1

  // ---- geometry chain (perm/rank needed by bn_apply_y scatter) ----
  build_grid  <<<(N_SITES+255)/256, 256, 0, stream>>>(coords, gridp);
  count_blocks<<<CNT_BLOCKS, 256, 0, stream>>>(gridp, blockcnt);
  scan_blocks <<<1, 1024, 0, stream>>>(blockcnt, blockoff);
  fill_perm   <<<CNT_BLOCKS, 256, 0, stream>>>(gridp, blockoff, perm, rank);

  // ---- BN chain ----
  bn_reduce      <<<RED_BLOCKS, 256, 0, stream>>>(feats, partial);
  bn_finalize_pad<<<1, 256, 0, stream>>>(partial, gamma, beta, ss, RED_BLOCKS,
                                         perm, (u32*)(yperm + (size_t)ZROW*32));
  bn_apply_y <<<2048, 256, 0, stream>>>((const float4*)feats, ss, rank, (uint4*)yperm);

  prep_wfrag<<<(KVOL*2*64*8 + 255)/256, 256, 0, stream>>>(wght, wf);

  conv_mfma<<<NSLOT/256, 256, 0, stream>>>(yperm, coords, wf, gridp, perm, out);
}

// Round 8
// 463.975 us; speedup vs baseline: 1.7005x; 1.1578x over previous
//
#include <hip/hip_runtime.h>

typedef unsigned short u16;
typedef unsigned int u32;
typedef unsigned long long u64;

#define N_SITES 500000
#define CIN 32
#define COUT 32
#define DD 128
#define HHH 128
#define WWW 128
#define KVOL 125
#define EPSV 1e-4f
#define NVOX (4*DD*HHH*WWW)           // 8,388,608 = 8192 * 1024
#define RED_BLOCKS 504
#define CNT_BLOCKS 8192
#define NSLOT 500224                  // 1954 * 256 (padded site slots)
#define ZROW  N_SITES                 // zero feature row index in yperm
#define SENTI (NVOX+4)                // sentinel window start (post-pad, all -1)

typedef short v8s __attribute__((ext_vector_type(8)));
typedef float v16f __attribute__((ext_vector_type(16)));

// ---------- helpers ----------
__device__ __forceinline__ u16 f2bf(float f){
  union { float f; u32 i; } v; v.f = f;
  u32 r = v.i + 0x7fffu + ((v.i >> 16) & 1u);
  return (u16)(r >> 16);
}

// ---------- BN stage 1: per-block partial sums (f32 input) ----------
__launch_bounds__(256)
__global__ void bn_reduce(const float* __restrict__ x, float* __restrict__ partial){
  __shared__ float ssum[8][32], ssq[8][32];
  int tid = threadIdx.x;
  int c   = tid & 31;
  int row = tid >> 5;
  float s = 0.f, q = 0.f;
  for(int site = blockIdx.x*8 + row; site < N_SITES; site += gridDim.x*8){
    float f = x[(size_t)site*32 + c];
    s += f; q += f*f;
  }
  ssum[row][c] = s; ssq[row][c] = q;
  __syncthreads();
  if(tid < 32){
    float ts = 0.f, tq = 0.f;
    #pragma unroll
    for(int r = 0; r < 8; r++){ ts += ssum[r][tid]; tq += ssq[r][tid]; }
    partial[blockIdx.x*64 + tid]      = ts;
    partial[blockIdx.x*64 + 32 + tid] = tq;
  }
}

// ---------- BN finalize + perm pad + zero-row (fused, 8-way parallel reduce) ----------
__global__ void bn_finalize_pad(const float* __restrict__ partial, const float* __restrict__ gamma,
                                const float* __restrict__ beta, float* __restrict__ ss, int nblk,
                                int* __restrict__ perm, u32* __restrict__ yzero){
  __shared__ float red[8][64];
  int tid = threadIdx.x;
  int c = tid & 31, r = tid >> 5;           // 8 block-stride rows
  float s = 0.f, q = 0.f;
  for(int b = r; b < nblk; b += 8){
    s += partial[b*64 + c];
    q += partial[b*64 + 32 + c];
  }
  red[r][c] = s; red[r][32 + c] = q;
  __syncthreads();
  if(tid < 32){
    float ts = 0.f, tq = 0.f;
    #pragma unroll
    for(int rr = 0; rr < 8; rr++){ ts += red[rr][tid]; tq += red[rr][32 + tid]; }
    float mean = ts / (float)N_SITES;
    float var  = tq / (float)N_SITES - mean*mean;   // biased, matches reference
    float scale = gamma[tid] * rsqrtf(var + EPSV);
    ss[tid]      = scale;
    ss[32 + tid] = beta[tid] - mean*scale;
  }
  if(tid < NSLOT - N_SITES) perm[N_SITES + tid] = perm[0];
  if(tid < 16) yzero[tid] = 0;                    // 64 B zero row at ZROW
}

// ---------- y = bf16(relu(x*scale+shift)) scattered into SLOT order ----------
__launch_bounds__(256)
__global__ void bn_apply_y(const float4* __restrict__ xv, const float* __restrict__ ss,
                           const int* __restrict__ rank, uint4* __restrict__ yv){
  __shared__ float sc[64];
  int tid = threadIdx.x;
  if(tid < 64) sc[tid] = ss[tid];
  __syncthreads();
  const int total = N_SITES*CIN/8;            // 2,000,000 chunks of 8
  int stride = gridDim.x*256;
  for(int i = blockIdx.x*256 + tid; i < total; i += stride){
    int c0 = (i & 3) * 8;
    int slot = rank[i >> 2];
    float4 a = xv[2*i], b = xv[2*i+1];
    float f[8] = {a.x,a.y,a.z,a.w,b.x,b.y,b.z,b.w};
    #pragma unroll
    for(int j = 0; j < 8; j++) f[j] = fmaxf(f[j]*sc[c0+j] + sc[32+c0+j], 0.f);
    uint4 o;
    o.x = ((u32)f2bf(f[1])<<16) | f2bf(f[0]);
    o.y = ((u32)f2bf(f[3])<<16) | f2bf(f[2]);
    o.z = ((u32)f2bf(f[5])<<16) | f2bf(f[4]);
    o.w = ((u32)f2bf(f[7])<<16) | f2bf(f[6]);
    yv[slot*4 + (i & 3)] = o;
  }
}

// ---------- scatter site indices into dense voxel grid ----------
__launch_bounds__(256)
__global__ void build_grid(const int4* __restrict__ coords, int* __restrict__ grid){
  int i = blockIdx.x*256 + threadIdx.x;
  if(i >= N_SITES) return;
  int4 c = coords[i];  // (b, z, y, x)
  grid[((c.x*DD + c.y)*HHH + c.z)*WWW + c.w] = i;
}

// ---------- per-1024-voxel-block active counts ----------
__launch_bounds__(256)
__global__ void count_blocks(const int* __restrict__ grid, int* __restrict__ blockcnt){
  int b = blockIdx.x, t = threadIdx.x;
  int cnt = 0;
  #pragma unroll
  for(int k = 0; k < 4; k++) cnt += (grid[b*1024 + k*256 + t] >= 0);
  #pragma unroll
  for(int o = 32; o > 0; o >>= 1) cnt += __shfl_down(cnt, o);
  __shared__ int wsum[4];
  if((t & 63) == 0) wsum[t >> 6] = cnt;
  __syncthreads();
  if(t == 0) blockcnt[b] = wsum[0] + wsum[1] + wsum[2] + wsum[3];
}

// ---------- exclusive prefix over 8192 block counts (shuffle scan, 2 barriers) ----------
__launch_bounds__(1024)
__global__ void scan_blocks(const int* __restrict__ blockcnt, int* __restrict__ blockoff){
  __shared__ int wsum[16];
  int t = threadIdx.x;
  int lane = t & 63, w = t >> 6;            // 16 waves
  int loc[8]; int v = 0;
  #pragma unroll
  for(int k = 0; k < 8; k++){ loc[k] = blockcnt[t*8 + k]; v += loc[k]; }
  // wave-level inclusive scan of v
  int s = v;
  #pragma unroll
  for(int o = 1; o < 64; o <<= 1){
    int u = __shfl_up(s, o);
    if(lane >= o) s += u;
  }
  if(lane == 63) wsum[w] = s;
  __syncthreads();
  if(w == 0 && lane < 16){
    int x = wsum[lane];
    #pragma unroll
    for(int o = 1; o < 16; o <<= 1){
      int u = __shfl_up(x, o);
      if(lane >= o) x += u;
    }
    wsum[lane] = x;
  }
  __syncthreads();
  int base = s - v + (w > 0 ? wsum[w - 1] : 0);
  #pragma unroll
  for(int k = 0; k < 8; k++){ blockoff[t*8 + k] = base; base += loc[k]; }
}

// ---------- ordered compaction: perm[slot]=site, rank[site]=slot, grid[v]:=slot ----------
__launch_bounds__(256)
__global__ void fill_perm(int* __restrict__ grid, const int* __restrict__ blockoff,
                          int* __restrict__ perm, int* __restrict__ rank){
  int b = blockIdx.x, t = threadIdx.x;
  int w = t >> 6, lane = t & 63;
  __shared__ int wcnt[4];
  __shared__ int carry;
  if(t == 0) carry = 0;
  __syncthreads();
  int base = blockoff[b];
  for(int p = 0; p < 4; p++){
    int v = b*1024 + p*256 + t;
    int s = grid[v];
    bool act = (s >= 0);
    u64 bal = __ballot(act);
    int pre = (int)__popcll(bal & ((1ull << lane) - 1ull));
    if(lane == 0) wcnt[w] = (int)__popcll(bal);
    __syncthreads();
    int woff = 0;
    for(int ww = 0; ww < w; ww++) woff += wcnt[ww];
    if(act){
      int slot = base + carry + woff + pre;
      perm[slot] = s;
      rank[s] = slot;
      grid[v] = slot;                       // voxel -> slot remap
    }
    int tot = wcnt[0] + wcnt[1] + wcnt[2] + wcnt[3];
    __syncthreads();
    if(t == 0) carry += tot;
    __syncthreads();
  }
}

// ---------- pack W f32 [125][cin][cout] into bf16 32x32x16 B-fragment order ----------
// wf element index i = ((off*2 + half)*64 + lane)*8 + j
// value = W[off][k][n], k = half*16 + (lane>>5)*8 + j, n = lane&31
__launch_bounds__(256)
__global__ void prep_wfrag(const float* __restrict__ w, u16* __restrict__ wf){
  int i = blockIdx.x*256 + threadIdx.x;
  if(i >= KVOL*2*64*8) return;
  int j    = i & 7;
  int lane = (i >> 3) & 63;
  int half = (i >> 9) & 1;
  int off  = i >> 10;
  int k = half*16 + ((lane >> 5) << 3) + j;
  int n = lane & 31;
  wf[i] = f2bf(w[off*1024 + k*32 + n]);
}

// ---------- submanifold sparse conv via MFMA gather-GEMM ----------
// v9 = v8 with LDS removed: per-row weight fragments loaded straight from
// global into registers (10 coalesced 1KB/wave insts per row, L2-hot; v5
// measured LDS-vs-global weights neutral). This deletes both per-plane
// barriers (waves drift freely) and lifts the 51.2KB LDS residency cap
// (3 blocks/CU, 29% occ) -> VGPR-class cap. launch_bounds(256,4) pins the
// <=128-VGPR class = 16 waves/CU (50%). v8's pipe accounting: MFMA 122k +
// VALU 93k + LDS 115k + L1 140k ~= 470k ~= 518k wall -> pipes don't overlap;
// concurrency (occupancy), not any one pipe, is the binding constraint.
__launch_bounds__(256, 4)
__global__ void conv_mfma(const u16* __restrict__ y, const int4* __restrict__ coords,
                          const u16* __restrict__ wf, const int* __restrict__ gridp,
                          const int* __restrict__ perm, float* __restrict__ out){
  const char* __restrict__ yc  = (const char*)y;
  const char* __restrict__ gcp = (const char*)gridp;
  const v8s*  __restrict__ wfv8 = (const v8s*)wf;

  int t = threadIdx.x;
  int l = t & 63;
  int r31 = l & 31;
  int h = l >> 5;
  u32 koff = (u32)h << 4;          // A k-half byte offset within a 64B row

  // bijective XCD swizzle
  int nwg = gridDim.x, bid = blockIdx.x;
  int xcd = bid & 7, rk = bid >> 3;
  int q8 = nwg >> 3, r8 = nwg & 7;
  int swz = (xcd < r8 ? xcd*(q8+1) : r8*(q8+1) + (xcd - r8)*q8) + rk;

  int slot = swz*256 + t;
  int p = perm[slot];
  int4 c = coords[p];                       // (b, z, y, x)
  int Z = c.y, Y = c.z, X = c.w;
  int base = ((c.x*DD + Z)*HHH + Y)*WWW + X;

  // per-group A-row site parameters (one-time redistribution)
  int b0 = __shfl(base, r31);
  int b1 = __shfl(base, 32 + r31);
  int x0 = __shfl(X, r31),  x1 = __shfl(X, 32 + r31);
  int y0 = __shfl(Y, r31),  y1 = __shfl(Y, 32 + r31);
  int z0 = __shfl(Z, r31),  z1 = __shfl(Z, 32 + r31);

  bool okx0[5], okx1[5], oky0[5], oky1[5];
  #pragma unroll
  for(int k = 0; k < 5; k++){
    okx0[k] = (u32)(x0 + k - 2) < WWW;
    okx1[k] = (u32)(x1 + k - 2) < WWW;
    oky0[k] = (u32)(y0 + k - 2) < HHH;
    oky1[k] = (u32)(y1 + k - 2) < HHH;
  }

  v16f acc0, acc1;
  #pragma unroll
  for(int i = 0; i < 16; i++){ acc0[i] = 0.f; acc1[i] = 0.f; }

  const int HW = HHH*WWW;

// issue the 4 window loads for row rr (both groups); raw regs stay in flight
#define PROBE_WIN(rr) { \
    bool zy0 = okz0 && oky0[rr]; \
    bool zy1 = okz1 && oky1[rr]; \
    int st0 = zy0 ? (pb0 + ((rr)-2)*WWW - 2) : SENTI; \
    int st1 = zy1 ? (pb1 + ((rr)-2)*WWW - 2) : SENTI; \
    int al0 = st0 & ~3, al1 = st1 & ~3; \
    sh0 = st0 - al0; sh1 = st1 - al1; \
    rA0 = *(const int4*)(gcp + (long)al0*4); \
    rA1 = *(const int4*)(gcp + (long)al0*4 + 16); \
    rB0 = *(const int4*)(gcp + (long)al1*4); \
    rB1 = *(const int4*)(gcp + (long)al1*4 + 16); \
  }

// extract 5 dx values per group from the raw windows (v4-verified tree)
#define EXTRACT(rr) { \
    int e0[8] = {rA0.x,rA0.y,rA0.z,rA0.w,rA1.x,rA1.y,rA1.z,rA1.w}; \
    int e1[8] = {rB0.x,rB0.y,rB0.z,rB0.w,rB1.x,rB1.y,rB1.z,rB1.w}; \
    bool sa2 = (sh0 & 2) != 0, sa1 = (sh0 & 1) != 0; \
    bool sb2 = (sh1 & 2) != 0, sb1 = (sh1 & 1) != 0; \
    _Pragma("unroll") \
    for(int k = 0; k < 5; k++){ \
      int t0 = sa2 ? e0[k+2] : e0[k]; \
      int t1 = sa2 ? e0[k+3] : e0[k+1]; \
      nvA[k] = okx0[k] ? (sa1 ? t1 : t0) : -1; \
      int u0 = sb2 ? e1[k+2] : e1[k]; \
      int u1 = sb2 ? e1[k+3] : e1[k+1]; \
      nvB[k] = okx1[k] ? (sb1 ? u1 : u0) : -1; \
    } \
  }

  #pragma unroll 1
  for(int dz = -2; dz <= 2; dz++){
    bool okz0 = (u32)(z0 + dz) < DD;
    bool okz1 = (u32)(z1 + dz) < DD;
    int pb0 = b0 + dz*HW, pb1 = b1 + dz*HW;

    int4 rA0, rA1, rB0, rB1;
    int sh0, sh1;
    PROBE_WIN(0)                            // row-0 windows issued at plane top
    asm volatile("" ::: "memory");

    // ---- row-pipelined: wb loads -> extract -> 20 gathers -> next windows -> MFMAs ----
    #pragma unroll
    for(int r = 0; r < 5; r++){
      // this row's 5 weight-fragment pairs, straight from global (L2-hot)
      const v8s* wrow = wfv8 + (u32)(((dz + 2)*5 + r)*5) * 128u;
      v8s wb[10];
      #pragma unroll
      for(int k = 0; k < 5; k++){
        wb[k*2+0] = wrow[k*128 + l];
        wb[k*2+1] = wrow[k*128 + 64 + l];
      }
      int nvA[5], nvB[5];
      EXTRACT(r)
      v8s fr[20];
      #pragma unroll
      for(int k = 0; k < 5; k++){
        u32 n0 = (u32)nvA[k], n1 = (u32)nvB[k];
        u32 rw0 = n0 < (u32)ZROW ? n0 : (u32)ZROW;   // invalid -> zero row
        u32 rw1 = n1 < (u32)ZROW ? n1 : (u32)ZROW;
        u32 ya0 = (rw0 << 6) + koff;
        u32 ya1 = (rw1 << 6) + koff;
        fr[k*4+0] = *(const v8s*)(yc + ya0);
        fr[k*4+1] = *(const v8s*)(yc + ya0 + 32u);
        fr[k*4+2] = *(const v8s*)(yc + ya1);
        fr[k*4+3] = *(const v8s*)(yc + ya1 + 32u);
      }
      asm volatile("" ::: "memory");        // pin: wb + gathers issued first
      if(r < 4){
        PROBE_WIN(r+1)                      // next row's windows hide under MFMAs
        asm volatile("" ::: "memory");
      }
      #pragma unroll
      for(int k = 0; k < 5; k++){
        acc0 = __builtin_amdgcn_mfma_f32_32x32x16_bf16(fr[k*4+0], wb[k*2+0], acc0, 0, 0, 0);
        acc0 = __builtin_amdgcn_mfma_f32_32x32x16_bf16(fr[k*4+1], wb[k*2+1], acc0, 0, 0, 0);
        acc1 = __builtin_amdgcn_mfma_f32_32x32x16_bf16(fr[k*4+2], wb[k*2+0], acc1, 0, 0, 0);
        acc1 = __builtin_amdgcn_mfma_f32_32x32x16_bf16(fr[k*4+3], wb[k*2+1], acc1, 0, 0, 0);
      }
    }
  }
#undef PROBE_WIN
#undef EXTRACT

  // epilogue: C/D layout col=lane&31, row=(reg&3)+8*(reg>>2)+4*(lane>>5)  [m74/m101]
  #pragma unroll
  for(int rg = 0; rg < 16; rg++){
    int row = (rg & 3) + ((rg >> 2) << 3) + (h << 2);
    int s0 = __shfl(p, row);
    int s1 = __shfl(p, 32 + row);
    out[(size_t)s0*32 + r31] = acc0[rg];
    out[(size_t)s1*32 + r31] = acc1[rg];
  }
}

extern "C" void kernel_launch(void* const* d_in, const int* in_sizes, int n_in,
                              void* d_out, int out_size, void* d_ws, size_t ws_size,
                              hipStream_t stream) {
  const float* feats  = (const float*)d_in[0];   // [N,32] f32
  const int4*  coords = (const int4*) d_in[1];   // [N,4] int32
  const float* gamma  = (const float*)d_in[2];   // [32] f32
  const float* beta   = (const float*)d_in[3];   // [32] f32
  const float* wght   = (const float*)d_in[4];   // [125,32,32] f32
  float* out = (float*)d_out;

  char* ws = (char*)d_ws;
  int*   grid_raw = (int*)  ws;                   // 33,554,560 B = (NVOX+32)*4 (8 pre + 24 post pad)
  int*   gridp    = grid_raw + 8;                 // usable grid [0, NVOX)
  u16*   yperm    = (u16*)  (ws + 33554560);      // 32,000,064 B (500001 rows, SLOT order)
  u16*   wf       = (u16*)  (ws + 65554624);      //    256,000 B
  int*   perm     = (int*)  (ws + 65810624);      //  2,000,896 B
  int*   blockcnt = (int*)  (ws + 67811520);      //     32,768 B
  int*   blockoff = (int*)  (ws + 67844288);      //     32,768 B
  float* partial  = (float*)(ws + 67877056);      //    129,024 B
  float* ss       = (float*)(ws + 68006080);      //        256 B
  // total: 68,006,336 B
  // rank[] (2MB) lives in the FIRST 2MB of d_out: written by fill_perm,
  // consumed by bn_apply_y, fully overwritten by conv_mfma afterwards.
  int* rank = (int*)d_out;

  hipMemsetAsync(grid_raw, 0xFF, (size_t)(NVOX+32)*4, stream);   // grid + pads = -1

  // ---- geometry chain (perm/rank needed by bn_apply_y scatter) ----
  build_grid  <<<(N_SITES+255)/256, 256, 0, stream>>>(coords, gridp);
  count_blocks<<<CNT_BLOCKS, 256, 0, stream>>>(gridp, blockcnt);
  scan_blocks <<<1, 1024, 0, stream>>>(blockcnt, blockoff);
  fill_perm   <<<CNT_BLOCKS, 256, 0, stream>>>(gridp, blockoff, perm, rank);

  // ---- BN chain ----
  bn_reduce      <<<RED_BLOCKS, 256, 0, stream>>>(feats, partial);
  bn_finalize_pad<<<1, 256, 0, stream>>>(partial, gamma, beta, ss, RED_BLOCKS,
                                         perm, (u32*)(yperm + (size_t)ZROW*32));
  bn_apply_y <<<2048, 256, 0, stream>>>((const float4*)feats, ss, rank, (uint4*)yperm);

  prep_wfrag<<<(KVOL*2*64*8 + 255)/256, 256, 0, stream>>>(wght, wf);

  conv_mfma<<<NSLOT/256, 256, 0, stream>>>(yperm, coords, wf, gridp, perm, out);
}

// Round 9
// 458.391 us; speedup vs baseline: 1.7212x; 1.0122x over previous
//
#include <hip/hip_runtime.h>

typedef unsigned short u16;
typedef unsigned int u32;
typedef unsigned long long u64;

#define N_SITES 500000
#define CIN 32
#define COUT 32
#define DD 128
#define HHH 128
#define WWW 128
#define KVOL 125
#define EPSV 1e-4f
#define NVOX (4*DD*HHH*WWW)           // 8,388,608 = 8192 * 1024
#define RED_BLOCKS 504
#define CNT_BLOCKS 8192
#define NSLOT 500224                  // 977 * 512 (padded site slots)
#define ZROW  N_SITES                 // zero feature row index in yperm
#define SENTI (NVOX+4)                // sentinel window start (post-pad, all -1)

typedef short v8s __attribute__((ext_vector_type(8)));
typedef float v16f __attribute__((ext_vector_type(16)));

// ---------- helpers ----------
__device__ __forceinline__ u16 f2bf(float f){
  union { float f; u32 i; } v; v.f = f;
  u32 r = v.i + 0x7fffu + ((v.i >> 16) & 1u);
  return (u16)(r >> 16);
}

// ---------- BN stage 1: per-block partial sums (f32 input) ----------
__launch_bounds__(256)
__global__ void bn_reduce(const float* __restrict__ x, float* __restrict__ partial){
  __shared__ float ssum[8][32], ssq[8][32];
  int tid = threadIdx.x;
  int c   = tid & 31;
  int row = tid >> 5;
  float s = 0.f, q = 0.f;
  for(int site = blockIdx.x*8 + row; site < N_SITES; site += gridDim.x*8){
    float f = x[(size_t)site*32 + c];
    s += f; q += f*f;
  }
  ssum[row][c] = s; ssq[row][c] = q;
  __syncthreads();
  if(tid < 32){
    float ts = 0.f, tq = 0.f;
    #pragma unroll
    for(int r = 0; r < 8; r++){ ts += ssum[r][tid]; tq += ssq[r][tid]; }
    partial[blockIdx.x*64 + tid]      = ts;
    partial[blockIdx.x*64 + 32 + tid] = tq;
  }
}

// ---------- BN finalize + perm pad + zero-row (fused, 8-way parallel reduce) ----------
__global__ void bn_finalize_pad(const float* __restrict__ partial, const float* __restrict__ gamma,
                                const float* __restrict__ beta, float* __restrict__ ss, int nblk,
                                int* __restrict__ perm, u32* __restrict__ yzero){
  __shared__ float red[8][64];
  int tid = threadIdx.x;
  int c = tid & 31, r = tid >> 5;           // 8 block-stride rows
  float s = 0.f, q = 0.f;
  for(int b = r; b < nblk; b += 8){
    s += partial[b*64 + c];
    q += partial[b*64 + 32 + c];
  }
  red[r][c] = s; red[r][32 + c] = q;
  __syncthreads();
  if(tid < 32){
    float ts = 0.f, tq = 0.f;
    #pragma unroll
    for(int rr = 0; rr < 8; rr++){ ts += red[rr][tid]; tq += red[rr][32 + tid]; }
    float mean = ts / (float)N_SITES;
    float var  = tq / (float)N_SITES - mean*mean;   // biased, matches reference
    float scale = gamma[tid] * rsqrtf(var + EPSV);
    ss[tid]      = scale;
    ss[32 + tid] = beta[tid] - mean*scale;
  }
  if(tid < NSLOT - N_SITES) perm[N_SITES + tid] = perm[0];
  if(tid < 16) yzero[tid] = 0;                    // 64 B zero row at ZROW
}

// ---------- y = bf16(relu(x*scale+shift)) scattered into SLOT order ----------
__launch_bounds__(256)
__global__ void bn_apply_y(const float4* __restrict__ xv, const float* __restrict__ ss,
                           const int* __restrict__ rank, uint4* __restrict__ yv){
  __shared__ float sc[64];
  int tid = threadIdx.x;
  if(tid < 64) sc[tid] = ss[tid];
  __syncthreads();
  const int total = N_SITES*CIN/8;            // 2,000,000 chunks of 8
  int stride = gridDim.x*256;
  for(int i = blockIdx.x*256 + tid; i < total; i += stride){
    int c0 = (i & 3) * 8;
    int slot = rank[i >> 2];
    float4 a = xv[2*i], b = xv[2*i+1];
    float f[8] = {a.x,a.y,a.z,a.w,b.x,b.y,b.z,b.w};
    #pragma unroll
    for(int j = 0; j < 8; j++) f[j] = fmaxf(f[j]*sc[c0+j] + sc[32+c0+j], 0.f);
    uint4 o;
    o.x = ((u32)f2bf(f[1])<<16) | f2bf(f[0]);
    o.y = ((u32)f2bf(f[3])<<16) | f2bf(f[2]);
    o.z = ((u32)f2bf(f[5])<<16) | f2bf(f[4]);
    o.w = ((u32)f2bf(f[7])<<16) | f2bf(f[6]);
    yv[slot*4 + (i & 3)] = o;
  }
}

// ---------- scatter site ids into dense grid + per-1024-block counts (fused) ----------
__launch_bounds__(256)
__global__ void build_grid(const int4* __restrict__ coords, int* __restrict__ grid,
                           int* __restrict__ blockcnt){
  int i = blockIdx.x*256 + threadIdx.x;
  if(i >= N_SITES) return;
  int4 c = coords[i];  // (b, z, y, x)
  int v = ((c.x*DD + c.y)*HHH + c.z)*WWW + c.w;
  grid[v] = i;
  atomicAdd(&blockcnt[v >> 10], 1);
}

// ---------- exclusive prefix over 8192 block counts (shuffle scan, 2 barriers) ----------
__launch_bounds__(1024)
__global__ void scan_blocks(const int* __restrict__ blockcnt, int* __restrict__ blockoff){
  __shared__ int wsum[16];
  int t = threadIdx.x;
  int lane = t & 63, w = t >> 6;            // 16 waves
  int loc[8]; int v = 0;
  #pragma unroll
  for(int k = 0; k < 8; k++){ loc[k] = blockcnt[t*8 + k]; v += loc[k]; }
  // wave-level inclusive scan of v
  int s = v;
  #pragma unroll
  for(int o = 1; o < 64; o <<= 1){
    int u = __shfl_up(s, o);
    if(lane >= o) s += u;
  }
  if(lane == 63) wsum[w] = s;
  __syncthreads();
  if(w == 0 && lane < 16){
    int x = wsum[lane];
    #pragma unroll
    for(int o = 1; o < 16; o <<= 1){
      int u = __shfl_up(x, o);
      if(lane >= o) x += u;
    }
    wsum[lane] = x;
  }
  __syncthreads();
  int base = s - v + (w > 0 ? wsum[w - 1] : 0);
  #pragma unroll
  for(int k = 0; k < 8; k++){ blockoff[t*8 + k] = base; base += loc[k]; }
}

// ---------- ordered compaction: perm[slot]=site, rank[site]=slot, grid[v]:=slot ----------
__launch_bounds__(256)
__global__ void fill_perm(int* __restrict__ grid, const int* __restrict__ blockoff,
                          int* __restrict__ perm, int* __restrict__ rank){
  int b = blockIdx.x, t = threadIdx.x;
  int w = t >> 6, lane = t & 63;
  __shared__ int wcnt[4];
  __shared__ int carry;
  if(t == 0) carry = 0;
  __syncthreads();
  int base = blockoff[b];
  for(int p = 0; p < 4; p++){
    int v = b*1024 + p*256 + t;
    int s = grid[v];
    bool act = (s >= 0);
    u64 bal = __ballot(act);
    int pre = (int)__popcll(bal & ((1ull << lane) - 1ull));
    if(lane == 0) wcnt[w] = (int)__popcll(bal);
    __syncthreads();
    int woff = 0;
    for(int ww = 0; ww < w; ww++) woff += wcnt[ww];
    if(act){
      int slot = base + carry + woff + pre;
      perm[slot] = s;
      rank[s] = slot;
      grid[v] = slot;                       // voxel -> slot remap
    }
    int tot = wcnt[0] + wcnt[1] + wcnt[2] + wcnt[3];
    __syncthreads();
    if(t == 0) carry += tot;
    __syncthreads();
  }
}

// ---------- pack W f32 [125][cin][cout] into bf16 32x32x16 B-fragment order ----------
// wf element index i = ((off*2 + half)*64 + lane)*8 + j
// value = W[off][k][n], k = half*16 + (lane>>5)*8 + j, n = lane&31
__launch_bounds__(256)
__global__ void prep_wfrag(const float* __restrict__ w, u16* __restrict__ wf){
  int i = blockIdx.x*256 + threadIdx.x;
  if(i >= KVOL*2*64*8) return;
  int j    = i & 7;
  int lane = (i >> 3) & 63;
  int half = (i >> 9) & 1;
  int off  = i >> 10;
  int k = half*16 + ((lane >> 5) << 3) + j;
  int n = lane & 31;
  wf[i] = f2bf(w[off*1024 + k*32 + n]);
}

// ---------- submanifold sparse conv via MFMA gather-GEMM ----------
// v10 = v8's LDS-weight kernel (216us) at 512 threads/block: same 51.2KB
// staging now amortized over 8 waves -> LDS cap becomes 3 blocks x 8 waves
// = 24 waves/CU (75%), double v8's 12; wf L2 traffic halves (977 blocks).
// v9 taught: occupancy alone doesn't pay if you ALSO add 250 wf VMEM insts
// + spills (v9: FETCH +17MB, WRITE +10MB, conv 216->251). So weights stay
// on the LDS pipe and there is NO VGPR cap (v8 measured 84 VGPR = exactly
// 6 waves/SIMD, matching the 24-wave LDS cap).
__launch_bounds__(512)
__global__ void conv_mfma(const u16* __restrict__ y, const int4* __restrict__ coords,
                          const u16* __restrict__ wf, const int* __restrict__ gridp,
                          const int* __restrict__ perm, float* __restrict__ out){
  const char* __restrict__ yc  = (const char*)y;
  const char* __restrict__ gcp = (const char*)gridp;
  __shared__ v8s swf[3200];                 // 51,200 B: [25 off][2 half][64 lane] x 16B

  int t = threadIdx.x;
  int l = t & 63;
  int r31 = l & 31;
  int h = l >> 5;
  u32 koff = (u32)h << 4;          // A k-half byte offset within a 64B row

  // bijective XCD swizzle
  int nwg = gridDim.x, bid = blockIdx.x;
  int xcd = bid & 7, rk = bid >> 3;
  int q8 = nwg >> 3, r8 = nwg & 7;
  int swz = (xcd < r8 ? xcd*(q8+1) : r8*(q8+1) + (xcd - r8)*q8) + rk;

  int slot = swz*512 + t;
  int p = perm[slot];
  int4 c = coords[p];                       // (b, z, y, x)
  int Z = c.y, Y = c.z, X = c.w;
  int base = ((c.x*DD + Z)*HHH + Y)*WWW + X;

  // per-group A-row site parameters (one-time redistribution)
  int b0 = __shfl(base, r31);
  int b1 = __shfl(base, 32 + r31);
  int x0 = __shfl(X, r31),  x1 = __shfl(X, 32 + r31);
  int y0 = __shfl(Y, r31),  y1 = __shfl(Y, 32 + r31);
  int z0 = __shfl(Z, r31),  z1 = __shfl(Z, 32 + r31);

  bool okx0[5], okx1[5], oky0[5], oky1[5];
  #pragma unroll
  for(int k = 0; k < 5; k++){
    okx0[k] = (u32)(x0 + k - 2) < WWW;
    okx1[k] = (u32)(x1 + k - 2) < WWW;
    oky0[k] = (u32)(y0 + k - 2) < HHH;
    oky1[k] = (u32)(y1 + k - 2) < HHH;
  }

  v16f acc0, acc1;
  #pragma unroll
  for(int i = 0; i < 16; i++){ acc0[i] = 0.f; acc1[i] = 0.f; }

  const int HW = HHH*WWW;
  const uint4* __restrict__ wfv = (const uint4*)wf;

// issue the 4 window loads for row rr (both groups); raw regs stay in flight
#define PROBE_WIN(rr) { \
    bool zy0 = okz0 && oky0[rr]; \
    bool zy1 = okz1 && oky1[rr]; \
    int st0 = zy0 ? (pb0 + ((rr)-2)*WWW - 2) : SENTI; \
    int st1 = zy1 ? (pb1 + ((rr)-2)*WWW - 2) : SENTI; \
    int al0 = st0 & ~3, al1 = st1 & ~3; \
    sh0 = st0 - al0; sh1 = st1 - al1; \
    rA0 = *(const int4*)(gcp + (long)al0*4); \
    rA1 = *(const int4*)(gcp + (long)al0*4 + 16); \
    rB0 = *(const int4*)(gcp + (long)al1*4); \
    rB1 = *(const int4*)(gcp + (long)al1*4 + 16); \
  }

// extract 5 dx values per group from the raw windows (v4-verified tree)
#define EXTRACT(rr) { \
    int e0[8] = {rA0.x,rA0.y,rA0.z,rA0.w,rA1.x,rA1.y,rA1.z,rA1.w}; \
    int e1[8] = {rB0.x,rB0.y,rB0.z,rB0.w,rB1.x,rB1.y,rB1.z,rB1.w}; \
    bool sa2 = (sh0 & 2) != 0, sa1 = (sh0 & 1) != 0; \
    bool sb2 = (sh1 & 2) != 0, sb1 = (sh1 & 1) != 0; \
    _Pragma("unroll") \
    for(int k = 0; k < 5; k++){ \
      int t0 = sa2 ? e0[k+2] : e0[k]; \
      int t1 = sa2 ? e0[k+3] : e0[k+1]; \
      nvA[k] = okx0[k] ? (sa1 ? t1 : t0) : -1; \
      int u0 = sb2 ? e1[k+2] : e1[k]; \
      int u1 = sb2 ? e1[k+3] : e1[k+1]; \
      nvB[k] = okx1[k] ? (sb1 ? u1 : u0) : -1; \
    } \
  }

  #pragma unroll 1
  for(int dz = -2; dz <= 2; dz++){
    bool okz0 = (u32)(z0 + dz) < DD;
    bool okz1 = (u32)(z1 + dz) < DD;
    int pb0 = b0 + dz*HW, pb1 = b1 + dz*HW;

    int4 rA0, rA1, rB0, rB1;
    int sh0, sh1;
    PROBE_WIN(0)                            // row-0 windows fly during staging
    asm volatile("" ::: "memory");

    __syncthreads();                        // prior plane's LDS reads complete
    // ---- stage this plane's 25 weight-fragment pairs into LDS ----
    {
      u32 pbase = (u32)((dz + 2) * 3200);   // in 16B chunks
      #pragma unroll
      for(int it = 0; it < 7; it++){
        int ch = it*512 + t;
        if(ch < 3200){
          uint4 v = wfv[pbase + ch];
          *(uint4*)&swf[ch] = v;
        }
      }
    }
    __syncthreads();                        // weights staged

    // ---- row-pipelined: extract -> 20 gathers -> next-row windows -> MFMAs ----
    #pragma unroll
    for(int r = 0; r < 5; r++){
      int nvA[5], nvB[5];
      EXTRACT(r)
      v8s fr[20];
      #pragma unroll
      for(int k = 0; k < 5; k++){
        u32 n0 = (u32)nvA[k], n1 = (u32)nvB[k];
        u32 rw0 = n0 < (u32)ZROW ? n0 : (u32)ZROW;   // invalid -> zero row
        u32 rw1 = n1 < (u32)ZROW ? n1 : (u32)ZROW;
        u32 ya0 = (rw0 << 6) + koff;
        u32 ya1 = (rw1 << 6) + koff;
        fr[k*4+0] = *(const v8s*)(yc + ya0);
        fr[k*4+1] = *(const v8s*)(yc + ya0 + 32u);
        fr[k*4+2] = *(const v8s*)(yc + ya1);
        fr[k*4+3] = *(const v8s*)(yc + ya1 + 32u);
      }
      asm volatile("" ::: "memory");        // pin: 20 gathers issued first
      if(r < 4){
        PROBE_WIN(r+1)                      // next row's windows hide under MFMAs
        asm volatile("" ::: "memory");
      }
      // process the row: weights from LDS, 20 MFMAs
      #pragma unroll
      for(int k = 0; k < 5; k++){
        int o = r*5 + k;
        v8s wb0 = swf[o*128 + l];           // ds_read_b128
        v8s wb1 = swf[o*128 + 64 + l];
        acc0 = __builtin_amdgcn_mfma_f32_32x32x16_bf16(fr[k*4+0], wb0, acc0, 0, 0, 0);
        acc0 = __builtin_amdgcn_mfma_f32_32x32x16_bf16(fr[k*4+1], wb1, acc0, 0, 0, 0);
        acc1 = __builtin_amdgcn_mfma_f32_32x32x16_bf16(fr[k*4+2], wb0, acc1, 0, 0, 0);
        acc1 = __builtin_amdgcn_mfma_f32_32x32x16_bf16(fr[k*4+3], wb1, acc1, 0, 0, 0);
      }
    }
  }
#undef PROBE_WIN
#undef EXTRACT

  // epilogue: C/D layout col=lane&31, row=(reg&3)+8*(reg>>2)+4*(lane>>5)  [m74/m101]
  #pragma unroll
  for(int rg = 0; rg < 16; rg++){
    int row = (rg & 3) + ((rg >> 2) << 3) + (h << 2);
    int s0 = __shfl(p, row);
    int s1 = __shfl(p, 32 + row);
    out[(size_t)s0*32 + r31] = acc0[rg];
    out[(size_t)s1*32 + r31] = acc1[rg];
  }
}

extern "C" void kernel_launch(void* const* d_in, const int* in_sizes, int n_in,
                              void* d_out, int out_size, void* d_ws, size_t ws_size,
                              hipStream_t stream) {
  const float* feats  = (const float*)d_in[0];   // [N,32] f32
  const int4*  coords = (const int4*) d_in[1];   // [N,4] int32
  const float* gamma  = (const float*)d_in[2];   // [32] f32
  const float* beta   = (const float*)d_in[3];   // [32] f32
  const float* wght   = (const float*)d_in[4];   // [125,32,32] f32
  float* out = (float*)d_out;

  char* ws = (char*)d_ws;
  int*   grid_raw = (int*)  ws;                   // 33,554,560 B = (NVOX+32)*4 (8 pre + 24 post pad)
  int*   gridp    = grid_raw + 8;                 // usable grid [0, NVOX)
  u16*   yperm    = (u16*)  (ws + 33554560);      // 32,000,064 B (500001 rows, SLOT order)
  u16*   wf       = (u16*)  (ws + 65554624);      //    256,000 B
  int*   perm     = (int*)  (ws + 65810624);      //  2,000,896 B
  int*   blockcnt = (int*)  (ws + 67811520);      //     32,768 B
  int*   blockoff = (int*)  (ws + 67844288);      //     32,768 B
  float* partial  = (float*)(ws + 67877056);      //    129,024 B
  float* ss       = (float*)(ws + 68006080);      //        256 B
  // total: 68,006,336 B
  // rank[] (2MB) lives in the FIRST 2MB of d_out: written by fill_perm,
  // consumed by bn_apply_y, fully overwritten by conv_mfma afterwards.
  int* rank = (int*)d_out;

  hipMemsetAsync(grid_raw, 0xFF, (size_t)(NVOX+32)*4, stream);   // grid + pads = -1
  hipMemsetAsync(blockcnt, 0, 32768, stream);                    // atomic counters

  // ---- geometry chain (perm/rank needed by bn_apply_y scatter) ----
  build_grid  <<<(N_SITES+255)/256, 256, 0, stream>>>(coords, gridp, blockcnt);
  scan_blocks <<<1, 1024, 0, stream>>>(blockcnt, blockoff);
  fill_perm   <<<CNT_BLOCKS, 256, 0, stream>>>(gridp, blockoff, perm, rank);

  // ---- BN chain ----
  bn_reduce      <<<RED_BLOCKS, 256, 0, stream>>>(feats, partial);
  bn_finalize_pad<<<1, 256, 0, stream>>>(partial, gamma, beta, ss, RED_BLOCKS,
                                         perm, (u32*)(yperm + (size_t)ZROW*32));
  bn_apply_y <<<2048, 256, 0, stream>>>((const float4*)feats, ss, rank, (uint4*)yperm);

  prep_wfrag<<<(KVOL*2*64*8 + 255)/256, 256, 0, stream>>>(wght, wf);

  conv_mfma<<<NSLOT/512, 512, 0, stream>>>(yperm, coords, wf, gridp, perm, out);
}